// Round 1
// baseline (919.678 us; speedup 1.0000x reference)
//
#include <hip/hip_runtime.h>
#include <math.h>

// ExpertSelectiveTimeVaryingSSM — MI355X
// Pipeline: prep (norms, f16 weight repacks, S^-1) -> pi -> uc -> scan (z recurrence,
// time-chunked with burn-in) -> y -> x.

static constexpr int BB = 64, TT = 1024;
static constexpr int NPOS = BB * TT;           // 65536

typedef _Float16 h1;
typedef _Float16 h2v __attribute__((ext_vector_type(2)));

__device__ __forceinline__ float fdot2(unsigned int a, unsigned int b, float c) {
  return __builtin_amdgcn_fdot2(__builtin_bit_cast(h2v, a), __builtin_bit_cast(h2v, b), c, false);
}
__device__ __forceinline__ unsigned short f2h(float x) {
  h1 h = (h1)x; return __builtin_bit_cast(unsigned short, h);
}
__device__ __forceinline__ float h2f(unsigned short x) {
  return (float)__builtin_bit_cast(h1, x);
}

// ---------------------------------------------------------------------------
// prep: blocks 0..7 = experts (power iteration for spectral norm, write scaled
// f16 repacks); block 8 = build S, invert (per-column forward substitution).
// Layouts: Ah[m][a][n] (row-major per expert, a,n<128)
//          Kuq[n<64][a<128][m<8]  (u->z block, cols 128..191 of K)
//          Cq [n<128][ay<64][m<8] (z->y block, rows 128..191 of K)
//          Sinvh[i][j] padded row stride 132 halves
// ---------------------------------------------------------------------------
__global__ void __launch_bounds__(256) prep_kernel(
    const float* __restrict__ K_raw, const float* __restrict__ S_raw,
    unsigned short* __restrict__ Ah, unsigned short* __restrict__ Kuq,
    unsigned short* __restrict__ Cq, unsigned short* __restrict__ Sinvh) {
  const int blk = blockIdx.x, tid = threadIdx.x;
  if (blk == 8) {
    __shared__ float Y[128 * 128];
    if (tid < 128) {
      const int c = tid;
      for (int i = 0; i < 128; ++i) {
        float dii = S_raw[i * 128 + i];
        float sp = (dii > 20.f) ? dii : log1pf(expf(dii));
        float sii = sp + 1e-3f;
        float s = (c == i) ? 1.0f : 0.0f;
        for (int j = 0; j < i; ++j) s -= S_raw[i * 128 + j] * Y[j * 128 + c];
        Y[i * 128 + c] = s / sii;
      }
    }
    __syncthreads();
    for (int idx = tid; idx < 128 * 132; idx += 256) {
      int i = idx / 132, j = idx - i * 132;
      float val = (j < 128) ? Y[i * 128 + j] : 0.f;
      Sinvh[idx] = f2h(val);
    }
    return;
  }
  const float* K = K_raw + blk * 36864;  // 192*192
  __shared__ float v[192], wv[192], red[256];
  if (tid < 192) v[tid] = 1.0f;
  __syncthreads();
  for (int it = 0; it < 14; ++it) {
    if (tid < 192) {
      float s = 0.f;
      const int nmax = (tid < 128) ? 192 : 128;  // zeroed block: r>=128 & n>=128
      for (int n = 0; n < nmax; ++n) s += K[tid * 192 + n] * v[n];
      wv[tid] = s;
    }
    __syncthreads();
    float nv = 0.f;
    if (tid < 192) {
      float s = 0.f;
      const int rmax = (tid < 128) ? 192 : 128;
      for (int r = 0; r < rmax; ++r) s += K[r * 192 + tid] * wv[r];
      nv = s;
    }
    red[tid] = nv * nv;
    __syncthreads();
    for (int st = 128; st > 0; st >>= 1) { if (tid < st) red[tid] += red[tid + st]; __syncthreads(); }
    float inv = rsqrtf(red[0] + 1e-30f);
    __syncthreads();
    if (tid < 192) v[tid] = nv * inv;
    __syncthreads();
  }
  {
    float s = 0.f;
    if (tid < 192) {
      const int nmax = (tid < 128) ? 192 : 128;
      for (int n = 0; n < nmax; ++n) s += K[tid * 192 + n] * v[n];
    }
    red[tid] = s * s;
    __syncthreads();
    for (int st = 128; st > 0; st >>= 1) { if (tid < st) red[tid] += red[tid + st]; __syncthreads(); }
  }
  const float sigma = sqrtf(red[0]);
  const float inv = (sigma > 1.0f) ? 1.0f / sigma : 1.0f;
  for (int idx = tid; idx < 16384; idx += 256) {       // Ah: a<128, n<128
    int a = idx >> 7, n = idx & 127;
    Ah[blk * 16384 + idx] = f2h(K[a * 192 + n] * inv);
  }
  for (int idx = tid; idx < 8192; idx += 256) {        // Kuq: n<64, a<128
    int n = idx >> 7, a = idx & 127;
    Kuq[(n * 128 + a) * 8 + blk] = f2h(K[a * 192 + 128 + n] * inv);
  }
  for (int idx = tid; idx < 8192; idx += 256) {        // Cq: n<128, ay<64
    int n = idx >> 6, ay = idx & 63;
    Cq[(n * 64 + ay) * 8 + blk] = f2h(K[(128 + ay) * 192 + n] * inv);
  }
}

// ---------------------------------------------------------------------------
// pi: softmax(gelu(u@gw1^T+gb1)@gw2^T+gb2). 512 blocks x 256 thr, 128 pos/blk.
// ---------------------------------------------------------------------------
__global__ void __launch_bounds__(256) pi_kernel(
    const float* __restrict__ u, const float* __restrict__ gw1,
    const float* __restrict__ gb1, const float* __restrict__ gw2,
    const float* __restrict__ gb2, float* __restrict__ pi) {
  __shared__ float gw1t[64 * 64];   // [n][l]
  __shared__ float gw2t[64 * 8];    // [l][m]
  __shared__ float gb1s[64];
  __shared__ float gb2s[8];
  __shared__ float us[4][64], hs[4][64];
  const int tid = threadIdx.x;
  for (int idx = tid; idx < 4096; idx += 256) {
    int l = idx >> 6, n = idx & 63;
    gw1t[n * 64 + l] = gw1[idx];
  }
  for (int idx = tid; idx < 512; idx += 256) {
    int m = idx >> 6, l = idx & 63;
    gw2t[l * 8 + m] = gw2[idx];
  }
  if (tid < 64) gb1s[tid] = gb1[tid];
  if (tid < 8) gb2s[tid] = gb2[tid];
  __syncthreads();
  const int wv = tid >> 6, ln = tid & 63;
  const int pbase = blockIdx.x * 128;
  for (int it = 0; it < 32; ++it) {
    const int p = pbase + it * 4 + wv;
    us[wv][ln] = u[p * 64 + ln];
    __syncthreads();
    float a = gb1s[ln];
    #pragma unroll 8
    for (int n = 0; n < 64; ++n) a += gw1t[n * 64 + ln] * us[wv][n];
    hs[wv][ln] = 0.5f * a * (1.0f + erff(a * 0.70710678118654752f));
    __syncthreads();
    if (ln < 8) {
      float lg = gb2s[ln];
      #pragma unroll 8
      for (int l = 0; l < 64; ++l) lg += gw2t[l * 8 + ln] * hs[wv][l];
      float mx = lg;
      for (int d = 1; d < 8; d <<= 1) mx = fmaxf(mx, __shfl_xor(mx, d, 64));
      float e = expf(lg - mx);
      float sm = e;
      for (int d = 1; d < 8; d <<= 1) sm += __shfl_xor(sm, d, 64);
      pi[p * 8 + ln] = e / sm;
    }
    __syncthreads();
  }
}

// ---------------------------------------------------------------------------
// uc[p][a] = sum_m pi[p][m] * sum_{n<64} Kuq * (g*u[p][n]).  f16 dot2.
// 1024 blocks x 256 thr, 64 pos/blk; thread=(a, half), acc[32] in regs.
// ---------------------------------------------------------------------------
__global__ void __launch_bounds__(256) uc_kernel(
    const float* __restrict__ u, const float* __restrict__ pi,
    const float* __restrict__ lgam, const unsigned short* __restrict__ Kuq,
    unsigned short* __restrict__ uc) {
  __shared__ __align__(16) unsigned short Kst[16 * 128 * 8];  // 32KB
  __shared__ __align__(16) unsigned short qst[64 * 16 * 8];   // 16KB [p][nl][m]
  const int tid = threadIdx.x;
  const int a = tid & 127, hh = tid >> 7;
  const int pbase = blockIdx.x * 64;
  const float g = expf(lgam[0]);
  float acc[32];
  #pragma unroll
  for (int i = 0; i < 32; ++i) acc[i] = 0.f;
  for (int ph = 0; ph < 4; ++ph) {
    const int n0 = ph * 16;
    {
      const uint4* src = (const uint4*)(Kuq + n0 * 1024);
      uint4* dst = (uint4*)Kst;
      for (int idx = tid; idx < 2048; idx += 256) dst[idx] = src[idx];
    }
    for (int idx = tid; idx < 8192; idx += 256) {
      int p = idx >> 7, rem = idx & 127;
      int nl = rem >> 3, m = rem & 7;
      float val = g * u[(pbase + p) * 64 + n0 + nl] * pi[(pbase + p) * 8 + m];
      qst[idx] = f2h(val);
    }
    __syncthreads();
    for (int nl = 0; nl < 16; ++nl) {
      const uint4 kv = *(const uint4*)&Kst[(nl * 128 + a) * 8];
      const unsigned short* qb = &qst[(hh * 32) * 128 + nl * 8];
      #pragma unroll
      for (int p = 0; p < 32; ++p) {
        const uint4 qv = *(const uint4*)&qb[p * 128];
        acc[p] = fdot2(kv.x, qv.x, acc[p]);
        acc[p] = fdot2(kv.y, qv.y, acc[p]);
        acc[p] = fdot2(kv.z, qv.z, acc[p]);
        acc[p] = fdot2(kv.w, qv.w, acc[p]);
      }
    }
    __syncthreads();
  }
  #pragma unroll
  for (int p = 0; p < 32; ++p)
    uc[(size_t)(pbase + hh * 32 + p) * 128 + a] = f2h(acc[p]);
}

// ---------------------------------------------------------------------------
// scan: z_{t+1} = (sum_m pi_m A_m) z_t + uc_t.  256 blocks (4 chunks x 64 batch)
// x 1024 thr; thread (m,a) holds A_m row a as 64 f16x2 VGPRs.  L=256, W=32
// burn-in (state memory decays as 0.55^k -> 6.5e-9 after 32 steps).
// ---------------------------------------------------------------------------
__global__ void __launch_bounds__(1024) scan_kernel(
    const float* __restrict__ pi, const unsigned short* __restrict__ uc,
    const unsigned short* __restrict__ Ah, unsigned short* __restrict__ zbuf) {
  const int L = 256, W = 32;
  const int b = blockIdx.x & 63, c = blockIdx.x >> 6;
  const int tid = threadIdx.x;
  const int m = tid >> 7, a = tid & 127;
  int t0 = c * L - W; if (t0 < 0) t0 = 0;
  const int tend = c * L + L;
  const int tstore = c * L;
  __shared__ __align__(16) unsigned short zh[128];
  __shared__ float e_lds[8 * 128];
  __shared__ float pi_lds[2][8];
  uint4 A[16];
  {
    const uint4* src = (const uint4*)(Ah + (size_t)(m * 128 + a) * 128);
    #pragma unroll
    for (int k = 0; k < 16; ++k) A[k] = src[k];
  }
  if (tid < 128) zh[tid] = 0;
  unsigned short ucn = 0;
  if (tid < 128) ucn = uc[(size_t)(b * TT + t0) * 128 + tid];
  if (tid < 8) pi_lds[0][tid] = pi[(size_t)(b * TT + t0) * 8 + tid];
  if (c == 0 && tid < 128) zbuf[(size_t)(b * TT) * 128 + tid] = 0;
  __syncthreads();
  for (int t = t0; t < tend; ++t) {
    const int par = (t - t0) & 1;
    const bool havenext = (t + 1 < tend);
    unsigned short ucn2 = 0;
    float pin2 = 0.f;
    if (havenext && tid < 128) ucn2 = uc[(size_t)(b * TT + t + 1) * 128 + tid];
    if (havenext && tid < 8)   pin2 = pi[(size_t)(b * TT + t + 1) * 8 + tid];
    float acc0 = 0.f, acc1 = 0.f;
    const uint4* zv4 = (const uint4*)zh;
    #pragma unroll
    for (int k = 0; k < 16; ++k) {
      const uint4 zv = zv4[k];
      if (k & 1) {
        acc1 = fdot2(A[k].x, zv.x, acc1);
        acc1 = fdot2(A[k].y, zv.y, acc1);
        acc1 = fdot2(A[k].z, zv.z, acc1);
        acc1 = fdot2(A[k].w, zv.w, acc1);
      } else {
        acc0 = fdot2(A[k].x, zv.x, acc0);
        acc0 = fdot2(A[k].y, zv.y, acc0);
        acc0 = fdot2(A[k].z, zv.z, acc0);
        acc0 = fdot2(A[k].w, zv.w, acc0);
      }
    }
    e_lds[m * 128 + a] = acc0 + acc1;
    __syncthreads();
    if (tid < 128) {
      float s = h2f(ucn);
      #pragma unroll
      for (int mm = 0; mm < 8; ++mm) s += pi_lds[par][mm] * e_lds[mm * 128 + tid];
      const unsigned short zs = f2h(s);
      zh[tid] = zs;
      const int t1 = t + 1;
      if (t1 < tend && t1 >= tstore) zbuf[(size_t)(b * TT + t1) * 128 + tid] = zs;
      ucn = ucn2;
    }
    if (tid < 8 && havenext) pi_lds[par ^ 1][tid] = pin2;
    __syncthreads();
  }
}

// ---------------------------------------------------------------------------
// y[p][ay] = sum_m pi[p][m] sum_{n<128} Cq * z[p][n].  1024 blocks, 64 pos/blk.
// ---------------------------------------------------------------------------
__global__ void __launch_bounds__(256) y_kernel(
    const float* __restrict__ pi, const unsigned short* __restrict__ zbuf,
    const unsigned short* __restrict__ Cq, float* __restrict__ yout) {
  __shared__ __align__(16) unsigned short Cst[32 * 64 * 8];  // 32KB
  __shared__ __align__(16) unsigned short qz[64 * 32 * 8];   // 32KB [p][nl][m]
  const int tid = threadIdx.x;
  const int ay = tid & 63, g4 = tid >> 6;
  const int pbase = blockIdx.x * 64;
  float acc[16];
  #pragma unroll
  for (int i = 0; i < 16; ++i) acc[i] = 0.f;
  for (int ph = 0; ph < 4; ++ph) {
    const int n0 = ph * 32;
    {
      const uint4* src = (const uint4*)(Cq + n0 * 512);
      uint4* dst = (uint4*)Cst;
      for (int idx = tid; idx < 2048; idx += 256) dst[idx] = src[idx];
    }
    for (int idx = tid; idx < 16384; idx += 256) {
      int p = idx >> 8, rem = idx & 255;
      int nl = rem >> 3, mq = rem & 7;
      float val = h2f(zbuf[(size_t)(pbase + p) * 128 + n0 + nl]) * pi[(size_t)(pbase + p) * 8 + mq];
      qz[idx] = f2h(val);
    }
    __syncthreads();
    for (int nl = 0; nl < 32; ++nl) {
      const uint4 cv = *(const uint4*)&Cst[(nl * 64 + ay) * 8];
      const unsigned short* qb = &qz[(g4 * 16) * 256 + nl * 8];
      #pragma unroll
      for (int p = 0; p < 16; ++p) {
        const uint4 qv = *(const uint4*)&qb[p * 256];
        acc[p] = fdot2(cv.x, qv.x, acc[p]);
        acc[p] = fdot2(cv.y, qv.y, acc[p]);
        acc[p] = fdot2(cv.z, qv.z, acc[p]);
        acc[p] = fdot2(cv.w, qv.w, acc[p]);
      }
    }
    __syncthreads();
  }
  #pragma unroll
  for (int p = 0; p < 16; ++p)
    yout[(size_t)(pbase + g4 * 16 + p) * 64 + ay] = acc[p];
}

// ---------------------------------------------------------------------------
// x[p][i] = sum_j Sinv[i][j] z[p][j].  2048 blocks, 32 pos/blk.
// Sinvh padded to 132 halves/row -> 2-way (free) LDS bank pattern on b64.
// ---------------------------------------------------------------------------
__global__ void __launch_bounds__(256) x_kernel(
    const unsigned short* __restrict__ zbuf, const unsigned short* __restrict__ Sinvh,
    float* __restrict__ xout) {
  __shared__ __align__(16) unsigned short Sst[128 * 132];  // 33792B
  __shared__ __align__(16) unsigned short zst[32 * 128];   // 8KB
  const int tid = threadIdx.x;
  const int i = tid & 127, hh = tid >> 7;
  const int pbase = blockIdx.x * 32;
  {
    const uint2* src = (const uint2*)Sinvh;
    uint2* dst = (uint2*)Sst;
    for (int idx = tid; idx < 4224; idx += 256) dst[idx] = src[idx];
  }
  {
    const uint4* src = (const uint4*)(zbuf + (size_t)pbase * 128);
    uint4* dst = (uint4*)zst;
    for (int idx = tid; idx < 512; idx += 256) dst[idx] = src[idx];
  }
  __syncthreads();
  for (int p = hh * 16; p < hh * 16 + 16; ++p) {
    float acc0 = 0.f, acc1 = 0.f;
    const unsigned short* srow = &Sst[i * 132];
    const unsigned short* zrow = &zst[p * 128];
    #pragma unroll
    for (int jj = 0; jj < 32; ++jj) {
      const uint2 sv = *(const uint2*)&srow[jj * 4];
      const uint2 zv = *(const uint2*)&zrow[jj * 4];
      acc0 = fdot2(sv.x, zv.x, acc0);
      acc1 = fdot2(sv.y, zv.y, acc1);
    }
    xout[(size_t)(pbase + p) * 128 + i] = acc0 + acc1;
  }
}

// ---------------------------------------------------------------------------
extern "C" void kernel_launch(void* const* d_in, const int* in_sizes, int n_in,
                              void* d_out, int out_size, void* d_ws, size_t ws_size,
                              hipStream_t stream) {
  const float* u      = (const float*)d_in[0];
  const float* K_raw  = (const float*)d_in[1];
  const float* lgam   = (const float*)d_in[2];
  const float* S_raw  = (const float*)d_in[3];
  const float* gw1    = (const float*)d_in[4];
  const float* gb1    = (const float*)d_in[5];
  const float* gw2    = (const float*)d_in[6];
  const float* gb2    = (const float*)d_in[7];

  char* w = (char*)d_ws;
  size_t off = 0;
  auto carve = [&](size_t bytes) -> void* {
    void* p = (void*)(w + off);
    off += (bytes + 255) & ~(size_t)255;
    return p;
  };
  float* pi            = (float*)carve((size_t)NPOS * 8 * 4);           // 2MB
  unsigned short* uc   = (unsigned short*)carve((size_t)NPOS * 128 * 2); // 16MB
  unsigned short* zbuf = (unsigned short*)carve((size_t)NPOS * 128 * 2); // 16MB
  unsigned short* Ah   = (unsigned short*)carve(8 * 128 * 128 * 2);
  unsigned short* Kuq  = (unsigned short*)carve(64 * 128 * 8 * 2);
  unsigned short* Cq   = (unsigned short*)carve(128 * 64 * 8 * 2);
  unsigned short* Svh  = (unsigned short*)carve(128 * 132 * 2);

  float* yout = (float*)d_out;
  float* xout = yout + (size_t)NPOS * 64;

  prep_kernel<<<dim3(9),    dim3(256),  0, stream>>>(K_raw, S_raw, Ah, Kuq, Cq, Svh);
  pi_kernel  <<<dim3(512),  dim3(256),  0, stream>>>(u, gw1, gb1, gw2, gb2, pi);
  uc_kernel  <<<dim3(1024), dim3(256),  0, stream>>>(u, pi, lgam, Kuq, uc);
  scan_kernel<<<dim3(256),  dim3(1024), 0, stream>>>(pi, uc, Ah, zbuf);
  y_kernel   <<<dim3(1024), dim3(256),  0, stream>>>(pi, zbuf, Cq, yout);
  x_kernel   <<<dim3(2048), dim3(256),  0, stream>>>(zbuf, Svh, xout);
}

// Round 2
// 596.375 us; speedup vs baseline: 1.5421x; 1.5421x over previous
//
#include <hip/hip_runtime.h>
#include <math.h>

// ExpertSelectiveTimeVaryingSSM — MI355X
// prep (LDS-staged norms + in-place S^-1) -> pi -> uc -> scan (MFMA batched
// z-recurrence, time-chunked w/ burn-in) -> y -> x.

static constexpr int BB = 64, TT = 1024;
static constexpr int NPOS = BB * TT;           // 65536

typedef _Float16 h1;
typedef _Float16 h2v  __attribute__((ext_vector_type(2)));
typedef _Float16 f16x8 __attribute__((ext_vector_type(8)));
typedef float    f32x4 __attribute__((ext_vector_type(4)));

__device__ __forceinline__ float fdot2(unsigned int a, unsigned int b, float c) {
  return __builtin_amdgcn_fdot2(__builtin_bit_cast(h2v, a), __builtin_bit_cast(h2v, b), c, false);
}
__device__ __forceinline__ unsigned short f2h(float x) {
  h1 h = (h1)x; return __builtin_bit_cast(unsigned short, h);
}
__device__ __forceinline__ float h2f(unsigned short x) {
  return (float)__builtin_bit_cast(h1, x);
}

// ---------------------------------------------------------------------------
// prep: blocks 0..7 = experts (LDS f16-staged power iteration, scaled repacks)
//       block 8 = S build + in-place LDS forward-substitution inverse.
// Layouts: Ah[m][a][n]; Kuq[n<64][a<128][m<8]; Cq[n<128][ay<64][m<8];
//          Sinvh[i][j] row stride 132 halves.
// ---------------------------------------------------------------------------
__global__ void __launch_bounds__(256) prep_kernel(
    const float* __restrict__ K_raw, const float* __restrict__ S_raw,
    unsigned short* __restrict__ Ah, unsigned short* __restrict__ Kuq,
    unsigned short* __restrict__ Cq, unsigned short* __restrict__ Sinvh) {
  __shared__ __align__(16) char pool[77312];
  const int blk = blockIdx.x, tid = threadIdx.x;
  if (blk == 8) {
    float* Sg   = (float*)pool;            // 128x128 f32, becomes Y = S^-1 in place
    float* invd = (float*)(pool + 65536);  // 128
    for (int idx = tid; idx < 16384; idx += 256) {
      int i = idx >> 7, j = idx & 127;
      Sg[idx] = (j <= i) ? S_raw[idx] : 0.f;   // zero strictly-upper
    }
    __syncthreads();
    if (tid < 128) {
      float d = Sg[tid * 128 + tid];
      float sp = (d > 20.f) ? d : log1pf(expf(d));
      invd[tid] = 1.f / (sp + 1e-3f);
    }
    __syncthreads();
    // forward substitution, thread tid = column; all LDS, in-place.
    for (int i = 0; i < 128; ++i) {
      float s = 0.f;
      if (tid < 128) {
        s = (tid == i) ? 1.f : 0.f;
        const float* srow = &Sg[i * 128];
        int j = 0;
        for (; j + 3 < i; j += 4)
          s -= srow[j]     * Sg[j * 128 + tid]       + srow[j + 1] * Sg[(j + 1) * 128 + tid]
             + srow[j + 2] * Sg[(j + 2) * 128 + tid] + srow[j + 3] * Sg[(j + 3) * 128 + tid];
        for (; j < i; ++j) s -= srow[j] * Sg[j * 128 + tid];
        s *= invd[i];
      }
      __syncthreads();            // all reads of row i done
      if (tid < 128) Sg[i * 128 + tid] = s;
      __syncthreads();            // writes visible
    }
    for (int idx = tid; idx < 128 * 132; idx += 256) {
      int i = idx / 132, j = idx - i * 132;
      Sinvh[idx] = f2h((j < 128) ? Sg[i * 128 + j] : 0.f);
    }
    return;
  }
  // ----- expert branch -----
  unsigned short* Kh = (unsigned short*)pool;   // [192][194] f16 (74496 B)
  float* vv  = (float*)(pool + 74496);          // 192
  float* wv  = vv + 192;                        // 192
  float* red = wv + 192;                        // 256
  const float* K = K_raw + blk * 36864;
  for (int idx = tid; idx < 36864; idx += 256) {
    int r = idx / 192, n = idx - r * 192;
    float kv = K[idx];
    if (r >= 128 && n >= 128) kv = 0.f;         // zeroed u->y block
    Kh[r * 194 + n] = f2h(kv);
  }
  for (int r = tid; r < 192; r += 256) { Kh[r * 194 + 192] = 0; Kh[r * 194 + 193] = 0; }
  if (tid < 192) vv[tid] = 1.f;
  __syncthreads();
  for (int it = 0; it < 14; ++it) {
    if (tid < 192) {
      float s = 0.f;
      const unsigned short* krow = &Kh[tid * 194];
      for (int n = 0; n < 192; ++n) s += h2f(krow[n]) * vv[n];
      wv[tid] = s;
    }
    __syncthreads();
    float nv = 0.f;
    if (tid < 192) {
      float s = 0.f;
      for (int r = 0; r < 192; ++r) s += h2f(Kh[r * 194 + tid]) * wv[r];
      nv = s;
    }
    red[tid] = nv * nv;
    __syncthreads();
    for (int st = 128; st > 0; st >>= 1) { if (tid < st) red[tid] += red[tid + st]; __syncthreads(); }
    float invn = rsqrtf(red[0] + 1e-30f);
    __syncthreads();
    if (tid < 192) vv[tid] = nv * invn;
    __syncthreads();
  }
  {
    float s = 0.f;
    if (tid < 192) {
      const unsigned short* krow = &Kh[tid * 194];
      for (int n = 0; n < 192; ++n) s += h2f(krow[n]) * vv[n];
    }
    red[tid] = s * s;
    __syncthreads();
    for (int st = 128; st > 0; st >>= 1) { if (tid < st) red[tid] += red[tid + st]; __syncthreads(); }
  }
  const float sigma = sqrtf(red[0]);
  const float inv = (sigma > 1.f) ? 1.f / sigma : 1.f;
  __syncthreads();
  for (int idx = tid; idx < 16384; idx += 256) {       // Ah: a<128, n<128
    int a = idx >> 7, n = idx & 127;
    Ah[blk * 16384 + idx] = f2h(h2f(Kh[a * 194 + n]) * inv);
  }
  for (int idx = tid; idx < 8192; idx += 256) {        // Kuq: n<64, a<128
    int n = idx >> 7, a = idx & 127;
    Kuq[(n * 128 + a) * 8 + blk] = f2h(h2f(Kh[a * 194 + 128 + n]) * inv);
  }
  for (int idx = tid; idx < 8192; idx += 256) {        // Cq: n<128, ay<64
    int n = idx >> 6, ay = idx & 63;
    Cq[(n * 64 + ay) * 8 + blk] = f2h(h2f(Kh[(128 + ay) * 194 + n]) * inv);
  }
}

// ---------------------------------------------------------------------------
// pi: softmax(gelu(u@gw1^T+gb1)@gw2^T+gb2). 512 blocks x 256 thr, 128 pos/blk.
// ---------------------------------------------------------------------------
__global__ void __launch_bounds__(256) pi_kernel(
    const float* __restrict__ u, const float* __restrict__ gw1,
    const float* __restrict__ gb1, const float* __restrict__ gw2,
    const float* __restrict__ gb2, float* __restrict__ pi) {
  __shared__ float gw1t[64 * 64];   // [n][l]
  __shared__ float gw2t[64 * 8];    // [l][m]
  __shared__ float gb1s[64];
  __shared__ float gb2s[8];
  __shared__ float us[4][64], hs[4][64];
  const int tid = threadIdx.x;
  for (int idx = tid; idx < 4096; idx += 256) {
    int l = idx >> 6, n = idx & 63;
    gw1t[n * 64 + l] = gw1[idx];
  }
  for (int idx = tid; idx < 512; idx += 256) {
    int m = idx >> 6, l = idx & 63;
    gw2t[l * 8 + m] = gw2[idx];
  }
  if (tid < 64) gb1s[tid] = gb1[tid];
  if (tid < 8) gb2s[tid] = gb2[tid];
  __syncthreads();
  const int wv = tid >> 6, ln = tid & 63;
  const int pbase = blockIdx.x * 128;
  for (int it = 0; it < 32; ++it) {
    const int p = pbase + it * 4 + wv;
    us[wv][ln] = u[p * 64 + ln];
    __syncthreads();
    float a = gb1s[ln];
    #pragma unroll 8
    for (int n = 0; n < 64; ++n) a += gw1t[n * 64 + ln] * us[wv][n];
    hs[wv][ln] = 0.5f * a * (1.0f + erff(a * 0.70710678118654752f));
    __syncthreads();
    if (ln < 8) {
      float lg = gb2s[ln];
      #pragma unroll 8
      for (int l = 0; l < 64; ++l) lg += gw2t[l * 8 + ln] * hs[wv][l];
      float mx = lg;
      for (int d = 1; d < 8; d <<= 1) mx = fmaxf(mx, __shfl_xor(mx, d, 64));
      float e = expf(lg - mx);
      float sm = e;
      for (int d = 1; d < 8; d <<= 1) sm += __shfl_xor(sm, d, 64);
      pi[p * 8 + ln] = e / sm;
    }
    __syncthreads();
  }
}

// ---------------------------------------------------------------------------
// uc[p][a] = sum_m pi[p][m] * sum_{n<64} Kuq * (g*u[p][n]).  f16 dot2.
// ---------------------------------------------------------------------------
__global__ void __launch_bounds__(256) uc_kernel(
    const float* __restrict__ u, const float* __restrict__ pi,
    const float* __restrict__ lgam, const unsigned short* __restrict__ Kuq,
    unsigned short* __restrict__ uc) {
  __shared__ __align__(16) unsigned short Kst[16 * 128 * 8];  // 32KB
  __shared__ __align__(16) unsigned short qst[64 * 16 * 8];   // 16KB [p][nl][m]
  const int tid = threadIdx.x;
  const int a = tid & 127, hh = tid >> 7;
  const int pbase = blockIdx.x * 64;
  const float g = expf(lgam[0]);
  float acc[32];
  #pragma unroll
  for (int i = 0; i < 32; ++i) acc[i] = 0.f;
  for (int ph = 0; ph < 4; ++ph) {
    const int n0 = ph * 16;
    {
      const uint4* src = (const uint4*)(Kuq + n0 * 1024);
      uint4* dst = (uint4*)Kst;
      for (int idx = tid; idx < 2048; idx += 256) dst[idx] = src[idx];
    }
    for (int idx = tid; idx < 8192; idx += 256) {
      int p = idx >> 7, rem = idx & 127;
      int nl = rem >> 3, m = rem & 7;
      float val = g * u[(pbase + p) * 64 + n0 + nl] * pi[(pbase + p) * 8 + m];
      qst[idx] = f2h(val);
    }
    __syncthreads();
    for (int nl = 0; nl < 16; ++nl) {
      const uint4 kv = *(const uint4*)&Kst[(nl * 128 + a) * 8];
      const unsigned short* qb = &qst[(hh * 32) * 128 + nl * 8];
      #pragma unroll
      for (int p = 0; p < 32; ++p) {
        const uint4 qv = *(const uint4*)&qb[p * 128];
        acc[p] = fdot2(kv.x, qv.x, acc[p]);
        acc[p] = fdot2(kv.y, qv.y, acc[p]);
        acc[p] = fdot2(kv.z, qv.z, acc[p]);
        acc[p] = fdot2(kv.w, qv.w, acc[p]);
      }
    }
    __syncthreads();
  }
  #pragma unroll
  for (int p = 0; p < 32; ++p)
    uc[(size_t)(pbase + hh * 32 + p) * 128 + a] = f2h(acc[p]);
}

// ---------------------------------------------------------------------------
// scan (MFMA): z_{t+1} = sum_m A_m (pi_m(b,t) z_t(b)) + uc(b,t) for 16 batches
// per block.  8 waves; wave w owns output rows [16w,16w+16).  A_m rows in VGPR
// (128/lane).  pi folded into B via v_pk_mul_f16 (batch = lane&15).  L=16,
// W=24 burn-in (||A_eff|| <= 0.554 -> 0.554^24 = 7e-7).  z history in LDS,
// coalesced writeout.  64 chunks x 4 batch-groups = 256 blocks.
// ---------------------------------------------------------------------------
static constexpr int LCH = 16, WBURN = 24;

__global__ void __launch_bounds__(512, 2) scan_kernel(
    const float* __restrict__ pi, const unsigned short* __restrict__ uc,
    const unsigned short* __restrict__ Ah, unsigned short* __restrict__ zbuf) {
  const int c = blockIdx.x >> 2, bg = blockIdx.x & 3;
  const int tid = threadIdx.x;
  const int w = tid >> 6, l = tid & 63, lb = l & 15, lg = l >> 4;
  const int tstore = c * LCH;
  int t0 = tstore - WBURN; if (t0 < 0) t0 = 0;
  const int tend = tstore + LCH;
  const int b0 = bg * 16;
  __shared__ __align__(16) unsigned short Zh[17 * 16 * 136];  // slot = z-time; [b][k] rows pad 136
  __shared__ __align__(16) unsigned short uc_lds[16 * 132];
  __shared__ float pi_lds[16 * 9];
  // A fragments: frag(m,kt): lane l holds A_m[16w + (l&15)][kt*32 + 8*(l>>4) + j]
  uint4 A[8][4];
  {
    const uint4* Ag = (const uint4*)Ah;
    const int rbase = (w * 16 + lb) * 16 + lg;
    #pragma unroll
    for (int m = 0; m < 8; ++m)
      #pragma unroll
      for (int kt = 0; kt < 4; ++kt)
        A[m][kt] = Ag[m * 2048 + rbase + kt * 4];
  }
  for (int i = tid; i < 2176; i += 512) { Zh[i] = 0; Zh[16 * 2176 + i] = 0; }
  {
    const int sb = tid >> 5, sj = (tid & 31) * 4;
    *(uint2*)&uc_lds[sb * 132 + sj] = *(const uint2*)&uc[((size_t)(b0 + sb) * TT + t0) * 128 + sj];
    if (tid < 128)
      pi_lds[(tid >> 3) * 9 + (tid & 7)] = pi[((size_t)(b0 + (tid >> 3)) * TT + t0) * 8 + (tid & 7)];
  }
  __syncthreads();
  const int row0 = w * 16 + lg * 4;
  for (int t = t0; t < tend; ++t) {
    const int t1 = t + 1;
    const int islot = (t  < tstore) ? 16 : (t  - tstore);
    const int oslot = (t1 < tstore) ? 16 : (t1 - tstore);
    const bool hv = (t1 < tend);
    const int sb = tid >> 5, sj = (tid & 31) * 4;
    uint2 ucn = make_uint2(0u, 0u);
    float pin = 0.f;
    if (hv) {                               // T14 issue-early
      ucn = *(const uint2*)&uc[((size_t)(b0 + sb) * TT + t1) * 128 + sj];
      if (tid < 128) pin = pi[((size_t)(b0 + (tid >> 3)) * TT + t1) * 8 + (tid & 7)];
    }
    uint4 zf[4];
    const unsigned short* zb = &Zh[islot * 2176 + lb * 136 + lg * 8];
    #pragma unroll
    for (int kt = 0; kt < 4; ++kt) zf[kt] = *(const uint4*)&zb[kt * 32];
    h1 pih[8];
    #pragma unroll
    for (int m = 0; m < 8; ++m) pih[m] = (h1)pi_lds[lb * 9 + m];
    f32x4 acc[4];
    #pragma unroll
    for (int q = 0; q < 4; ++q) acc[q] = (f32x4){0.f, 0.f, 0.f, 0.f};
    #pragma unroll
    for (int m = 0; m < 8; ++m) {
      #pragma unroll
      for (int kt = 0; kt < 4; ++kt) {
        f16x8 bf = __builtin_bit_cast(f16x8, zf[kt]) * pih[m];
        acc[m & 3] = __builtin_amdgcn_mfma_f32_16x16x32_f16(
            __builtin_bit_cast(f16x8, A[m][kt]), bf, acc[m & 3], 0, 0, 0);
      }
    }
    unsigned short zh4[4];
    #pragma unroll
    for (int r = 0; r < 4; ++r) {
      float s = acc[0][r] + acc[1][r] + acc[2][r] + acc[3][r];
      s += h2f(uc_lds[lb * 132 + row0 + r]);
      zh4[r] = f2h(s);
    }
    __syncthreads();                        // step-t reads done
    {
      uint2 zp;
      zp.x = (unsigned)zh4[0] | ((unsigned)zh4[1] << 16);
      zp.y = (unsigned)zh4[2] | ((unsigned)zh4[3] << 16);
      *(uint2*)&Zh[oslot * 2176 + lb * 136 + row0] = zp;
    }
    if (hv) {                               // T14 write-late
      *(uint2*)&uc_lds[sb * 132 + sj] = ucn;
      if (tid < 128) pi_lds[(tid >> 3) * 9 + (tid & 7)] = pin;
    }
    __syncthreads();
  }
  // coalesced writeout of slots 0..L-1  (slot 0 of chunk 0 = z_0 = 0)
  {
    const int pair = tid >> 1, q = tid & 1, s = pair >> 4, bb2 = pair & 15;
    const unsigned short* src = &Zh[s * 2176 + bb2 * 136 + q * 64];
    unsigned short* dst = &zbuf[((size_t)(b0 + bb2) * TT + tstore + s) * 128 + q * 64];
    #pragma unroll
    for (int k = 0; k < 8; ++k) ((uint4*)dst)[k] = ((const uint4*)src)[k];
  }
}

// ---------------------------------------------------------------------------
// y[p][ay] = sum_m pi[p][m] sum_{n<128} Cq * z[p][n].  1024 blocks, 64 pos/blk.
// ---------------------------------------------------------------------------
__global__ void __launch_bounds__(256) y_kernel(
    const float* __restrict__ pi, const unsigned short* __restrict__ zbuf,
    const unsigned short* __restrict__ Cq, float* __restrict__ yout) {
  __shared__ __align__(16) unsigned short Cst[32 * 64 * 8];  // 32KB
  __shared__ __align__(16) unsigned short qz[64 * 32 * 8];   // 32KB [p][nl][m]
  const int tid = threadIdx.x;
  const int ay = tid & 63, g4 = tid >> 6;
  const int pbase = blockIdx.x * 64;
  float acc[16];
  #pragma unroll
  for (int i = 0; i < 16; ++i) acc[i] = 0.f;
  for (int ph = 0; ph < 4; ++ph) {
    const int n0 = ph * 32;
    {
      const uint4* src = (const uint4*)(Cq + n0 * 512);
      uint4* dst = (uint4*)Cst;
      for (int idx = tid; idx < 2048; idx += 256) dst[idx] = src[idx];
    }
    for (int idx = tid; idx < 16384; idx += 256) {
      int p = idx >> 8, rem = idx & 255;
      int nl = rem >> 3, mq = rem & 7;
      float val = h2f(zbuf[(size_t)(pbase + p) * 128 + n0 + nl]) * pi[(size_t)(pbase + p) * 8 + mq];
      qz[idx] = f2h(val);
    }
    __syncthreads();
    for (int nl = 0; nl < 32; ++nl) {
      const uint4 cv = *(const uint4*)&Cst[(nl * 64 + ay) * 8];
      const unsigned short* qb = &qz[(g4 * 16) * 256 + nl * 8];
      #pragma unroll
      for (int p = 0; p < 16; ++p) {
        const uint4 qv = *(const uint4*)&qb[p * 256];
        acc[p] = fdot2(cv.x, qv.x, acc[p]);
        acc[p] = fdot2(cv.y, qv.y, acc[p]);
        acc[p] = fdot2(cv.z, qv.z, acc[p]);
        acc[p] = fdot2(cv.w, qv.w, acc[p]);
      }
    }
    __syncthreads();
  }
  #pragma unroll
  for (int p = 0; p < 16; ++p)
    yout[(size_t)(pbase + g4 * 16 + p) * 64 + ay] = acc[p];
}

// ---------------------------------------------------------------------------
// x[p][i] = sum_j Sinv[i][j] z[p][j].  2048 blocks, 32 pos/blk.
// ---------------------------------------------------------------------------
__global__ void __launch_bounds__(256) x_kernel(
    const unsigned short* __restrict__ zbuf, const unsigned short* __restrict__ Sinvh,
    float* __restrict__ xout) {
  __shared__ __align__(16) unsigned short Sst[128 * 132];  // 33792B
  __shared__ __align__(16) unsigned short zst[32 * 128];   // 8KB
  const int tid = threadIdx.x;
  const int i = tid & 127, hh = tid >> 7;
  const int pbase = blockIdx.x * 32;
  {
    const uint2* src = (const uint2*)Sinvh;
    uint2* dst = (uint2*)Sst;
    for (int idx = tid; idx < 4224; idx += 256) dst[idx] = src[idx];
  }
  {
    const uint4* src = (const uint4*)(zbuf + (size_t)pbase * 128);
    uint4* dst = (uint4*)zst;
    for (int idx = tid; idx < 512; idx += 256) dst[idx] = src[idx];
  }
  __syncthreads();
  for (int p = hh * 16; p < hh * 16 + 16; ++p) {
    float acc0 = 0.f, acc1 = 0.f;
    const unsigned short* srow = &Sst[i * 132];
    const unsigned short* zrow = &zst[p * 128];
    #pragma unroll
    for (int jj = 0; jj < 32; ++jj) {
      const uint2 sv = *(const uint2*)&srow[jj * 4];
      const uint2 zv = *(const uint2*)&zrow[jj * 4];
      acc0 = fdot2(sv.x, zv.x, acc0);
      acc1 = fdot2(sv.y, zv.y, acc1);
    }
    xout[(size_t)(pbase + p) * 128 + i] = acc0 + acc1;
  }
}

// ---------------------------------------------------------------------------
extern "C" void kernel_launch(void* const* d_in, const int* in_sizes, int n_in,
                              void* d_out, int out_size, void* d_ws, size_t ws_size,
                              hipStream_t stream) {
  const float* u      = (const float*)d_in[0];
  const float* K_raw  = (const float*)d_in[1];
  const float* lgam   = (const float*)d_in[2];
  const float* S_raw  = (const float*)d_in[3];
  const float* gw1    = (const float*)d_in[4];
  const float* gb1    = (const float*)d_in[5];
  const float* gw2    = (const float*)d_in[6];
  const float* gb2    = (const float*)d_in[7];

  char* w = (char*)d_ws;
  size_t off = 0;
  auto carve = [&](size_t bytes) -> void* {
    void* p = (void*)(w + off);
    off += (bytes + 255) & ~(size_t)255;
    return p;
  };
  float* pi            = (float*)carve((size_t)NPOS * 8 * 4);            // 2MB
  unsigned short* uc   = (unsigned short*)carve((size_t)NPOS * 128 * 2); // 16MB
  unsigned short* zbuf = (unsigned short*)carve((size_t)NPOS * 128 * 2); // 16MB
  unsigned short* Ah   = (unsigned short*)carve(8 * 128 * 128 * 2);
  unsigned short* Kuq  = (unsigned short*)carve(64 * 128 * 8 * 2);
  unsigned short* Cq   = (unsigned short*)carve(128 * 64 * 8 * 2);
  unsigned short* Svh  = (unsigned short*)carve(128 * 132 * 2);

  float* yout = (float*)d_out;
  float* xout = yout + (size_t)NPOS * 64;

  prep_kernel<<<dim3(9),    dim3(256),  0, stream>>>(K_raw, S_raw, Ah, Kuq, Cq, Svh);
  pi_kernel  <<<dim3(512),  dim3(256),  0, stream>>>(u, gw1, gb1, gw2, gb2, pi);
  uc_kernel  <<<dim3(1024), dim3(256),  0, stream>>>(u, pi, lgam, Kuq, uc);
  scan_kernel<<<dim3(256),  dim3(512),  0, stream>>>(pi, uc, Ah, zbuf);
  y_kernel   <<<dim3(1024), dim3(256),  0, stream>>>(pi, zbuf, Cq, yout);
  x_kernel   <<<dim3(2048), dim3(256),  0, stream>>>(zbuf, Svh, xout);
}

// Round 3
// 324.067 us; speedup vs baseline: 2.8379x; 1.8403x over previous
//
#include <hip/hip_runtime.h>
#include <math.h>

// ExpertSelectiveTimeVaryingSSM — MI355X
// prep -> pi -> uc (MFMA) -> scan (MFMA) -> y (MFMA) -> x (MFMA).
// Math: z_{t+1} = sum_m pi_m A_m z_t + uc_t ;  y_t = sum_m pi_m C_m z_t ;
//       x_t = S^-1 z_t.  Flattened k = n*8+m folds the pi-weighted expert sum
//       into plain GEMMs for uc and y.

static constexpr int BB = 64, TT = 1024;
static constexpr int NPOS = BB * TT;           // 65536

typedef _Float16 h1;
typedef _Float16 h2v  __attribute__((ext_vector_type(2)));
typedef _Float16 f16x8 __attribute__((ext_vector_type(8)));
typedef float    f32x4 __attribute__((ext_vector_type(4)));

__device__ __forceinline__ unsigned short f2h(float x) {
  h1 h = (h1)x; return __builtin_bit_cast(unsigned short, h);
}
__device__ __forceinline__ float h2f(unsigned short x) {
  return (float)__builtin_bit_cast(h1, x);
}
__device__ __forceinline__ f32x4 mfma16(uint4 a, uint4 b, f32x4 c) {
  return __builtin_amdgcn_mfma_f32_16x16x32_f16(
      __builtin_bit_cast(f16x8, a), __builtin_bit_cast(f16x8, b), c, 0, 0, 0);
}

// ---------------------------------------------------------------------------
// prep: blocks 0..7 = experts (LDS f16-staged power iteration, scaled repacks)
//       block 8 = S build + in-place LDS forward-substitution inverse.
// Layouts: Ah[m][a][n] (scan A);  Kuqw[a][n*8+m] (uc A, K=512);
//          Cw[ay][n*8+m] (y A, K=1024);  Sinvh[i][j] plain [128][128].
// ---------------------------------------------------------------------------
__global__ void __launch_bounds__(256) prep_kernel(
    const float* __restrict__ K_raw, const float* __restrict__ S_raw,
    unsigned short* __restrict__ Ah, unsigned short* __restrict__ Kuqw,
    unsigned short* __restrict__ Cw, unsigned short* __restrict__ Sinvh) {
  __shared__ __align__(16) char pool[77312];
  const int blk = blockIdx.x, tid = threadIdx.x;
  if (blk == 8) {
    float* Sg   = (float*)pool;            // 128x128 f32, becomes S^-1 in place
    float* invd = (float*)(pool + 65536);  // 128
    for (int idx = tid; idx < 16384; idx += 256) {
      int i = idx >> 7, j = idx & 127;
      Sg[idx] = (j <= i) ? S_raw[idx] : 0.f;
    }
    __syncthreads();
    if (tid < 128) {
      float d = Sg[tid * 128 + tid];
      float sp = (d > 20.f) ? d : log1pf(expf(d));
      invd[tid] = 1.f / (sp + 1e-3f);
    }
    __syncthreads();
    for (int i = 0; i < 128; ++i) {
      float s = 0.f;
      if (tid < 128) {
        s = (tid == i) ? 1.f : 0.f;
        const float* srow = &Sg[i * 128];
        int j = 0;
        for (; j + 3 < i; j += 4)
          s -= srow[j]     * Sg[j * 128 + tid]       + srow[j + 1] * Sg[(j + 1) * 128 + tid]
             + srow[j + 2] * Sg[(j + 2) * 128 + tid] + srow[j + 3] * Sg[(j + 3) * 128 + tid];
        for (; j < i; ++j) s -= srow[j] * Sg[j * 128 + tid];
        s *= invd[i];
      }
      __syncthreads();
      if (tid < 128) Sg[i * 128 + tid] = s;
      __syncthreads();
    }
    for (int idx = tid; idx < 16384; idx += 256) Sinvh[idx] = f2h(Sg[idx]);
    return;
  }
  // ----- expert branch -----
  unsigned short* Kh = (unsigned short*)pool;   // [192][194] f16
  float* vv  = (float*)(pool + 74496);
  float* wv  = vv + 192;
  float* red = wv + 192;
  const float* K = K_raw + blk * 36864;
  for (int idx = tid; idx < 36864; idx += 256) {
    int r = idx / 192, n = idx - r * 192;
    float kv = K[idx];
    if (r >= 128 && n >= 128) kv = 0.f;
    Kh[r * 194 + n] = f2h(kv);
  }
  for (int r = tid; r < 192; r += 256) { Kh[r * 194 + 192] = 0; Kh[r * 194 + 193] = 0; }
  if (tid < 192) vv[tid] = 1.f;
  __syncthreads();
  for (int it = 0; it < 14; ++it) {
    if (tid < 192) {
      float s = 0.f;
      const unsigned short* krow = &Kh[tid * 194];
      for (int n = 0; n < 192; ++n) s += h2f(krow[n]) * vv[n];
      wv[tid] = s;
    }
    __syncthreads();
    float nv = 0.f;
    if (tid < 192) {
      float s = 0.f;
      for (int r = 0; r < 192; ++r) s += h2f(Kh[r * 194 + tid]) * wv[r];
      nv = s;
    }
    red[tid] = nv * nv;
    __syncthreads();
    for (int st = 128; st > 0; st >>= 1) { if (tid < st) red[tid] += red[tid + st]; __syncthreads(); }
    float invn = rsqrtf(red[0] + 1e-30f);
    __syncthreads();
    if (tid < 192) vv[tid] = nv * invn;
    __syncthreads();
  }
  {
    float s = 0.f;
    if (tid < 192) {
      const unsigned short* krow = &Kh[tid * 194];
      for (int n = 0; n < 192; ++n) s += h2f(krow[n]) * vv[n];
    }
    red[tid] = s * s;
    __syncthreads();
    for (int st = 128; st > 0; st >>= 1) { if (tid < st) red[tid] += red[tid + st]; __syncthreads(); }
  }
  const float sigma = sqrtf(red[0]);
  const float inv = (sigma > 1.f) ? 1.f / sigma : 1.f;
  __syncthreads();
  for (int idx = tid; idx < 16384; idx += 256) {       // Ah: [m][a][n]
    int a = idx >> 7, n = idx & 127;
    Ah[blk * 16384 + idx] = f2h(h2f(Kh[a * 194 + n]) * inv);
  }
  for (int idx = tid; idx < 8192; idx += 256) {        // Kuqw: [a][n*8+m]
    int a = idx >> 6, n = idx & 63;
    Kuqw[a * 512 + n * 8 + blk] = f2h(h2f(Kh[a * 194 + 128 + n]) * inv);
  }
  for (int idx = tid; idx < 8192; idx += 256) {        // Cw: [ay][n*8+m]
    int ay = idx >> 7, n = idx & 127;
    Cw[ay * 1024 + n * 8 + blk] = f2h(h2f(Kh[(128 + ay) * 194 + n]) * inv);
  }
}

// ---------------------------------------------------------------------------
// pi: softmax(gelu(u@gw1^T+gb1)@gw2^T+gb2). 512 blocks x 256 thr, 128 pos/blk.
// ---------------------------------------------------------------------------
__global__ void __launch_bounds__(256) pi_kernel(
    const float* __restrict__ u, const float* __restrict__ gw1,
    const float* __restrict__ gb1, const float* __restrict__ gw2,
    const float* __restrict__ gb2, float* __restrict__ pi) {
  __shared__ float gw1t[64 * 64];   // [n][l]
  __shared__ float gw2t[64 * 8];    // [l][m]
  __shared__ float gb1s[64];
  __shared__ float gb2s[8];
  __shared__ float us[4][64], hs[4][64];
  const int tid = threadIdx.x;
  for (int idx = tid; idx < 4096; idx += 256) {
    int l = idx >> 6, n = idx & 63;
    gw1t[n * 64 + l] = gw1[idx];
  }
  for (int idx = tid; idx < 512; idx += 256) {
    int m = idx >> 6, l = idx & 63;
    gw2t[l * 8 + m] = gw2[idx];
  }
  if (tid < 64) gb1s[tid] = gb1[tid];
  if (tid < 8) gb2s[tid] = gb2[tid];
  __syncthreads();
  const int wv = tid >> 6, ln = tid & 63;
  const int pbase = blockIdx.x * 128;
  for (int it = 0; it < 32; ++it) {
    const int p = pbase + it * 4 + wv;
    us[wv][ln] = u[p * 64 + ln];
    __syncthreads();
    float a = gb1s[ln];
    #pragma unroll 8
    for (int n = 0; n < 64; ++n) a += gw1t[n * 64 + ln] * us[wv][n];
    hs[wv][ln] = 0.5f * a * (1.0f + erff(a * 0.70710678118654752f));
    __syncthreads();
    if (ln < 8) {
      float lg = gb2s[ln];
      #pragma unroll 8
      for (int l = 0; l < 64; ++l) lg += gw2t[l * 8 + ln] * hs[wv][l];
      float mx = lg;
      for (int d = 1; d < 8; d <<= 1) mx = fmaxf(mx, __shfl_xor(mx, d, 64));
      float e = expf(lg - mx);
      float sm = e;
      for (int d = 1; d < 8; d <<= 1) sm += __shfl_xor(sm, d, 64);
      pi[p * 8 + ln] = e / sm;
    }
    __syncthreads();
  }
}

// ---------------------------------------------------------------------------
// uc (MFMA): uc[p][a] = sum_{k=n*8+m} Kuqw[a][k] * (g u[p][n] pi[p][m]).
// M=128 (8 waves x 16 rows, A in 64 VGPR/lane), K=512, 16-pos tiles.
// 512 blocks x 512 thr, 128 pos/blk.
// ---------------------------------------------------------------------------
__global__ void __launch_bounds__(512) uc_kernel(
    const float* __restrict__ u, const float* __restrict__ pi,
    const float* __restrict__ lgam, const unsigned short* __restrict__ Kuqw,
    unsigned short* __restrict__ uc) {
  __shared__ __align__(16) unsigned short q[16][520];   // [col][k] pad->4-bank col spacing
  __shared__ float us[16][68];
  __shared__ float ps[16][9];
  const int tid = threadIdx.x;
  const int w = tid >> 6, l = tid & 63, arow = l & 15, lg = l >> 4;
  const int p0 = blockIdx.x * 128;
  const float g = expf(lgam[0]);
  uint4 A[16];
  {
    const uint4* Ag = (const uint4*)(Kuqw + (size_t)(16 * w + arow) * 512);
    #pragma unroll
    for (int kt = 0; kt < 16; ++kt) A[kt] = Ag[kt * 4 + lg];
  }
  const int bcol = tid & 15, sub = tid >> 4;            // build role: 16 cols x 32 n-pairs
  for (int tile = 0; tile < 8; ++tile) {
    const int pb = p0 + tile * 16;
    {
      const int pos = tid >> 5, np = tid & 31;
      float2 uv = *(const float2*)&u[(size_t)(pb + pos) * 64 + np * 2];
      us[pos][np * 2]     = g * uv.x;
      us[pos][np * 2 + 1] = g * uv.y;
      if (tid < 128) ps[tid >> 3][tid & 7] = pi[(size_t)(pb + (tid >> 3)) * 8 + (tid & 7)];
    }
    __syncthreads();
    {
      float u0 = us[bcol][2 * sub], u1 = us[bcol][2 * sub + 1];
      unsigned short tmp[16];
      #pragma unroll
      for (int m = 0; m < 8; ++m) {
        float pm = ps[bcol][m];
        tmp[m]     = f2h(u0 * pm);
        tmp[8 + m] = f2h(u1 * pm);
      }
      uint4* dst = (uint4*)&q[bcol][sub * 16];
      dst[0] = *(uint4*)&tmp[0];
      dst[1] = *(uint4*)&tmp[8];
    }
    __syncthreads();
    f32x4 acc = {0.f, 0.f, 0.f, 0.f};
    #pragma unroll
    for (int kt = 0; kt < 16; ++kt) {
      uint4 bf = *(const uint4*)&q[arow][kt * 32 + lg * 8];
      acc = mfma16(A[kt], bf, acc);
    }
    {
      uint2 zp;
      zp.x = (unsigned)f2h(acc[0]) | ((unsigned)f2h(acc[1]) << 16);
      zp.y = (unsigned)f2h(acc[2]) | ((unsigned)f2h(acc[3]) << 16);
      *(uint2*)&uc[(size_t)(pb + arow) * 128 + 16 * w + lg * 4] = zp;
    }
    __syncthreads();
  }
}

// ---------------------------------------------------------------------------
// scan (MFMA): z_{t+1} = sum_m A_m (pi_m z_t) + uc_t, 16 batches/block.
// ---------------------------------------------------------------------------
static constexpr int LCH = 16, WBURN = 24;

__global__ void __launch_bounds__(512, 2) scan_kernel(
    const float* __restrict__ pi, const unsigned short* __restrict__ uc,
    const unsigned short* __restrict__ Ah, unsigned short* __restrict__ zbuf) {
  const int c = blockIdx.x >> 2, bg = blockIdx.x & 3;
  const int tid = threadIdx.x;
  const int w = tid >> 6, l = tid & 63, lb = l & 15, lg = l >> 4;
  const int tstore = c * LCH;
  int t0 = tstore - WBURN; if (t0 < 0) t0 = 0;
  const int tend = tstore + LCH;
  const int b0 = bg * 16;
  __shared__ __align__(16) unsigned short Zh[17 * 16 * 136];
  __shared__ __align__(16) unsigned short uc_lds[16 * 132];
  __shared__ float pi_lds[16 * 9];
  uint4 A[8][4];
  {
    const uint4* Ag = (const uint4*)Ah;
    const int rbase = (w * 16 + lb) * 16 + lg;
    #pragma unroll
    for (int m = 0; m < 8; ++m)
      #pragma unroll
      for (int kt = 0; kt < 4; ++kt)
        A[m][kt] = Ag[m * 2048 + rbase + kt * 4];
  }
  for (int i = tid; i < 2176; i += 512) { Zh[i] = 0; Zh[16 * 2176 + i] = 0; }
  {
    const int sb = tid >> 5, sj = (tid & 31) * 4;
    *(uint2*)&uc_lds[sb * 132 + sj] = *(const uint2*)&uc[((size_t)(b0 + sb) * TT + t0) * 128 + sj];
    if (tid < 128)
      pi_lds[(tid >> 3) * 9 + (tid & 7)] = pi[((size_t)(b0 + (tid >> 3)) * TT + t0) * 8 + (tid & 7)];
  }
  __syncthreads();
  const int row0 = w * 16 + lg * 4;
  for (int t = t0; t < tend; ++t) {
    const int t1 = t + 1;
    const int islot = (t  < tstore) ? 16 : (t  - tstore);
    const int oslot = (t1 < tstore) ? 16 : (t1 - tstore);
    const bool hv = (t1 < tend);
    const int sb = tid >> 5, sj = (tid & 31) * 4;
    uint2 ucn = make_uint2(0u, 0u);
    float pin = 0.f;
    if (hv) {
      ucn = *(const uint2*)&uc[((size_t)(b0 + sb) * TT + t1) * 128 + sj];
      if (tid < 128) pin = pi[((size_t)(b0 + (tid >> 3)) * TT + t1) * 8 + (tid & 7)];
    }
    uint4 zf[4];
    const unsigned short* zb = &Zh[islot * 2176 + lb * 136 + lg * 8];
    #pragma unroll
    for (int kt = 0; kt < 4; ++kt) zf[kt] = *(const uint4*)&zb[kt * 32];
    h1 pih[8];
    #pragma unroll
    for (int m = 0; m < 8; ++m) pih[m] = (h1)pi_lds[lb * 9 + m];
    f32x4 acc[4];
    #pragma unroll
    for (int qq = 0; qq < 4; ++qq) acc[qq] = (f32x4){0.f, 0.f, 0.f, 0.f};
    #pragma unroll
    for (int m = 0; m < 8; ++m) {
      #pragma unroll
      for (int kt = 0; kt < 4; ++kt) {
        f16x8 bf = __builtin_bit_cast(f16x8, zf[kt]) * pih[m];
        acc[m & 3] = __builtin_amdgcn_mfma_f32_16x16x32_f16(
            __builtin_bit_cast(f16x8, A[m][kt]), bf, acc[m & 3], 0, 0, 0);
      }
    }
    unsigned short zh4[4];
    #pragma unroll
    for (int r = 0; r < 4; ++r) {
      float s = acc[0][r] + acc[1][r] + acc[2][r] + acc[3][r];
      s += h2f(uc_lds[lb * 132 + row0 + r]);
      zh4[r] = f2h(s);
    }
    __syncthreads();
    {
      uint2 zp;
      zp.x = (unsigned)zh4[0] | ((unsigned)zh4[1] << 16);
      zp.y = (unsigned)zh4[2] | ((unsigned)zh4[3] << 16);
      *(uint2*)&Zh[oslot * 2176 + lb * 136 + row0] = zp;
    }
    if (hv) {
      *(uint2*)&uc_lds[sb * 132 + sj] = ucn;
      if (tid < 128) pi_lds[(tid >> 3) * 9 + (tid & 7)] = pin;
    }
    __syncthreads();
  }
  {
    const int pair = tid >> 1, qq = tid & 1, s = pair >> 4, bb2 = pair & 15;
    const unsigned short* src = &Zh[s * 2176 + bb2 * 136 + qq * 64];
    unsigned short* dst = &zbuf[((size_t)(b0 + bb2) * TT + tstore + s) * 128 + qq * 64];
    #pragma unroll
    for (int k = 0; k < 8; ++k) ((uint4*)dst)[k] = ((const uint4*)src)[k];
  }
}

// ---------------------------------------------------------------------------
// y (MFMA): y[p][ay] = sum_{k=n*8+m} Cw[ay][k] * (z[p][n] pi[p][m]).
// M=64 (4 waves x 16 rows, A in 128 VGPR/lane), K=1024, 16-pos tiles.
// 512 blocks x 256 thr, 128 pos/blk.
// ---------------------------------------------------------------------------
__global__ void __launch_bounds__(256) y_kernel(
    const float* __restrict__ pi, const unsigned short* __restrict__ zbuf,
    const unsigned short* __restrict__ Cw, float* __restrict__ yout) {
  __shared__ __align__(16) unsigned short q[16][1032];
  __shared__ __align__(16) unsigned short zs[16][136];
  __shared__ float ps[16][9];
  const int tid = threadIdx.x;
  const int w = tid >> 6, l = tid & 63, arow = l & 15, lg = l >> 4;
  const int p0 = blockIdx.x * 128;
  uint4 A[32];
  {
    const uint4* Ag = (const uint4*)(Cw + (size_t)(16 * w + arow) * 1024);
    #pragma unroll
    for (int kt = 0; kt < 32; ++kt) A[kt] = Ag[kt * 4 + lg];
  }
  const int bcol = tid & 15, sub = tid >> 4;            // build: 16 cols x 16 n-octets
  for (int tile = 0; tile < 8; ++tile) {
    const int pb = p0 + tile * 16;
    {
      const int pos = tid >> 4, seg = tid & 15;
      *(uint4*)&zs[pos][seg * 8] = *(const uint4*)&zbuf[(size_t)(pb + pos) * 128 + seg * 8];
      if (tid < 128) ps[tid >> 3][tid & 7] = pi[(size_t)(pb + (tid >> 3)) * 8 + (tid & 7)];
    }
    __syncthreads();
    {
      unsigned short zarr[8];
      *(uint4*)zarr = *(const uint4*)&zs[bcol][sub * 8];
      float pm[8];
      #pragma unroll
      for (int m = 0; m < 8; ++m) pm[m] = ps[bcol][m];
      #pragma unroll
      for (int nn = 0; nn < 8; ++nn) {
        float zf = h2f(zarr[nn]);
        unsigned short tmp[8];
        #pragma unroll
        for (int m = 0; m < 8; ++m) tmp[m] = f2h(zf * pm[m]);
        *(uint4*)&q[bcol][sub * 64 + nn * 8] = *(uint4*)tmp;
      }
    }
    __syncthreads();
    f32x4 acc = {0.f, 0.f, 0.f, 0.f};
    #pragma unroll
    for (int kt = 0; kt < 32; ++kt) {
      uint4 bf = *(const uint4*)&q[arow][kt * 32 + lg * 8];
      acc = mfma16(A[kt], bf, acc);
    }
    *(f32x4*)&yout[(size_t)(pb + arow) * 64 + 16 * w + lg * 4] = acc;
    __syncthreads();
  }
}

// ---------------------------------------------------------------------------
// x (MFMA): x[p][i] = sum_j Sinv[i][j] z[p][j].  M=128 (8 waves), K=128.
// B-frags load straight from zbuf (coalesced uint4) — no LDS.
// 512 blocks x 512 thr, 128 pos/blk.
// ---------------------------------------------------------------------------
__global__ void __launch_bounds__(512) x_kernel(
    const unsigned short* __restrict__ zbuf, const unsigned short* __restrict__ Sinvh,
    float* __restrict__ xout) {
  const int tid = threadIdx.x;
  const int w = tid >> 6, l = tid & 63, arow = l & 15, lg = l >> 4;
  const int p0 = blockIdx.x * 128;
  uint4 A[4];
  {
    const uint4* Ag = (const uint4*)(Sinvh + (size_t)(16 * w + arow) * 128);
    #pragma unroll
    for (int kt = 0; kt < 4; ++kt) A[kt] = Ag[kt * 4 + lg];
  }
  for (int tile = 0; tile < 8; ++tile) {
    const int pb = p0 + tile * 16;
    const uint4* Z = (const uint4*)(zbuf + (size_t)(pb + arow) * 128);
    f32x4 acc = {0.f, 0.f, 0.f, 0.f};
    #pragma unroll
    for (int kt = 0; kt < 4; ++kt) {
      acc = mfma16(A[kt], Z[kt * 4 + lg], acc);
    }
    *(f32x4*)&xout[(size_t)(pb + arow) * 128 + 16 * w + lg * 4] = acc;
  }
}

// ---------------------------------------------------------------------------
extern "C" void kernel_launch(void* const* d_in, const int* in_sizes, int n_in,
                              void* d_out, int out_size, void* d_ws, size_t ws_size,
                              hipStream_t stream) {
  const float* u      = (const float*)d_in[0];
  const float* K_raw  = (const float*)d_in[1];
  const float* lgam   = (const float*)d_in[2];
  const float* S_raw  = (const float*)d_in[3];
  const float* gw1    = (const float*)d_in[4];
  const float* gb1    = (const float*)d_in[5];
  const float* gw2    = (const float*)d_in[6];
  const float* gb2    = (const float*)d_in[7];

  char* w = (char*)d_ws;
  size_t off = 0;
  auto carve = [&](size_t bytes) -> void* {
    void* p = (void*)(w + off);
    off += (bytes + 255) & ~(size_t)255;
    return p;
  };
  float* pi            = (float*)carve((size_t)NPOS * 8 * 4);            // 2MB
  unsigned short* uc   = (unsigned short*)carve((size_t)NPOS * 128 * 2); // 16MB
  unsigned short* zbuf = (unsigned short*)carve((size_t)NPOS * 128 * 2); // 16MB
  unsigned short* Ah   = (unsigned short*)carve(8 * 128 * 128 * 2);
  unsigned short* Kuqw = (unsigned short*)carve(128 * 512 * 2);
  unsigned short* Cw   = (unsigned short*)carve(64 * 1024 * 2);
  unsigned short* Svh  = (unsigned short*)carve(128 * 128 * 2);

  float* yout = (float*)d_out;
  float* xout = yout + (size_t)NPOS * 64;

  prep_kernel<<<dim3(9),    dim3(256),  0, stream>>>(K_raw, S_raw, Ah, Kuqw, Cw, Svh);
  pi_kernel  <<<dim3(512),  dim3(256),  0, stream>>>(u, gw1, gb1, gw2, gb2, pi);
  uc_kernel  <<<dim3(512),  dim3(512),  0, stream>>>(u, pi, lgam, Kuqw, uc);
  scan_kernel<<<dim3(256),  dim3(512),  0, stream>>>(pi, uc, Ah, zbuf);
  y_kernel   <<<dim3(512),  dim3(256),  0, stream>>>(pi, zbuf, Cw, yout);
  x_kernel   <<<dim3(512),  dim3(512),  0, stream>>>(zbuf, Svh, xout);
}

// Round 4
// 279.287 us; speedup vs baseline: 3.2930x; 1.1603x over previous
//
#include <hip/hip_runtime.h>
#include <math.h>

// ExpertSelectiveTimeVaryingSSM — MI355X
// prep_expert + prep_sinv -> pi -> uc (MFMA) -> scan (MFMA) -> y (MFMA) -> x (MFMA).
// Math: z_{t+1} = sum_m pi_m A_m z_t + uc_t ;  y_t = sum_m pi_m C_m z_t ;
//       x_t = S^-1 z_t.  Flattened k = n*8+m folds the pi-weighted expert sum
//       into plain GEMMs for uc and y.

static constexpr int BB = 64, TT = 1024;
static constexpr int NPOS = BB * TT;           // 65536

typedef _Float16 h1;
typedef _Float16 h2v  __attribute__((ext_vector_type(2)));
typedef _Float16 f16x8 __attribute__((ext_vector_type(8)));
typedef float    f32x4 __attribute__((ext_vector_type(4)));

__device__ __forceinline__ float fdot2(unsigned int a, unsigned int b, float c) {
  return __builtin_amdgcn_fdot2(__builtin_bit_cast(h2v, a), __builtin_bit_cast(h2v, b), c, false);
}
__device__ __forceinline__ unsigned short f2h(float x) {
  h1 h = (h1)x; return __builtin_bit_cast(unsigned short, h);
}
__device__ __forceinline__ float h2f(unsigned short x) {
  return (float)__builtin_bit_cast(h1, x);
}
__device__ __forceinline__ f32x4 mfma16(uint4 a, uint4 b, f32x4 c) {
  return __builtin_amdgcn_mfma_f32_16x16x32_f16(
      __builtin_bit_cast(f16x8, a), __builtin_bit_cast(f16x8, b), c, 0, 0, 0);
}

// ---------------------------------------------------------------------------
// prep_expert: 8 blocks x 768 thr.  Power iteration on K^T K with K and K^T
// both f16-staged in LDS (row stride 200 halves: 16B-aligned, bank-uniform).
// 4 lanes per row, fdot2 inner product.  No per-iter normalization (stored
// vectors scaled x2 per matvec to hold f16 range); Rayleigh at the end.
// Outputs: Ah[m][a][n]; Kuqw[a][n*8+m] (K=512); Cw[ay][n*8+m] (K=1024).
// ---------------------------------------------------------------------------
__global__ void __launch_bounds__(768) prep_expert_kernel(
    const float* __restrict__ K_raw, unsigned short* __restrict__ Ah,
    unsigned short* __restrict__ Kuqw, unsigned short* __restrict__ Cw) {
  __shared__ __align__(16) unsigned short Kh[192 * 200];   // 76800 B
  __shared__ __align__(16) unsigned short KhT[192 * 200];  // 76800 B
  __shared__ __align__(16) unsigned short vh[200];
  __shared__ __align__(16) unsigned short wh[200];
  __shared__ float red[256];
  const int blk = blockIdx.x, tid = threadIdx.x;
  const float* K = K_raw + blk * 36864;
  for (int idx = tid; idx < 36864; idx += 768) {
    int r = idx / 192, n = idx - r * 192;
    float kv = K[idx];
    if (r >= 128 && n >= 128) kv = 0.f;      // zeroed u->y block
    unsigned short h = f2h(kv);
    Kh[r * 200 + n] = h;
    KhT[n * 200 + r] = h;
  }
  {
    const uint4 z4 = make_uint4(0u, 0u, 0u, 0u);
    for (int r = tid; r < 192; r += 768) {
      *(uint4*)&Kh[r * 200 + 192] = z4;
      *(uint4*)&KhT[r * 200 + 192] = z4;
    }
    if (tid < 8) { vh[192 + tid] = 0; wh[192 + tid] = 0; }
    if (tid < 192) vh[tid] = f2h(1.f);
  }
  __syncthreads();
  const int r = tid >> 2, q = tid & 3;       // 768 = 192 rows x 4 quarters
  auto matvec = [&](const unsigned short* M, const unsigned short* src,
                    unsigned short* dst) {
    float acc = 0.f;
    const uint4* Mr = (const uint4*)(M + r * 200 + 48 * q);
    const uint4* Vv = (const uint4*)(src + 48 * q);
    #pragma unroll
    for (int j = 0; j < 6; ++j) {
      uint4 mv = Mr[j], sv = Vv[j];
      acc = fdot2(mv.x, sv.x, acc);
      acc = fdot2(mv.y, sv.y, acc);
      acc = fdot2(mv.z, sv.z, acc);
      acc = fdot2(mv.w, sv.w, acc);
    }
    acc += __shfl_xor(acc, 1, 64);
    acc += __shfl_xor(acc, 2, 64);
    if (q == 0) dst[r] = f2h(2.f * acc);     // x2 keeps f16 range w/o renorm
  };
  for (int it = 0; it < 9; ++it) {
    matvec(Kh, vh, wh);  __syncthreads();
    matvec(KhT, wh, vh); __syncthreads();
  }
  matvec(Kh, vh, wh);  __syncthreads();      // final half-step: w = 2 K v
  float aw = (tid < 192) ? h2f(wh[tid]) : 0.f;
  float av = (tid < 192) ? h2f(vh[tid]) : 0.f;
  if (tid < 256) red[tid] = aw * aw;
  __syncthreads();
  for (int st = 128; st > 0; st >>= 1) { if (tid < st) red[tid] += red[tid + st]; __syncthreads(); }
  const float nw2 = red[0];
  __syncthreads();
  if (tid < 256) red[tid] = av * av;
  __syncthreads();
  for (int st = 128; st > 0; st >>= 1) { if (tid < st) red[tid] += red[tid + st]; __syncthreads(); }
  const float nv2 = red[0];
  const float sigma = sqrtf(nw2 / (4.f * nv2 + 1e-30f));   // ||Kv||/||v||
  const float inv = (sigma > 1.f) ? 1.f / sigma : 1.f;
  __syncthreads();
  for (int idx = tid; idx < 16384; idx += 768) {       // Ah: [m][a][n]
    int a = idx >> 7, n = idx & 127;
    Ah[blk * 16384 + idx] = f2h(h2f(Kh[a * 200 + n]) * inv);
  }
  for (int idx = tid; idx < 8192; idx += 768) {        // Kuqw: [a][n*8+m]
    int a = idx >> 6, n = idx & 63;
    Kuqw[a * 512 + n * 8 + blk] = f2h(h2f(Kh[a * 200 + 128 + n]) * inv);
  }
  for (int idx = tid; idx < 8192; idx += 768) {        // Cw: [ay][n*8+m]
    int ay = idx >> 7, n = idx & 127;
    Cw[ay * 1024 + n * 8 + blk] = f2h(h2f(Kh[(128 + ay) * 200 + n]) * inv);
  }
}

// ---------------------------------------------------------------------------
// prep_sinv: 1 block x 256 thr.  Blocked forward substitution (BS=8):
// bulk acc = S[rows, <J] . Y[<J] as a parallel LDS matmul (Y column-major,
// pad 134), then 8 register-unrolled serial steps per block.
// ---------------------------------------------------------------------------
__global__ void __launch_bounds__(256) prep_sinv_kernel(
    const float* __restrict__ S_raw, unsigned short* __restrict__ Sinvh) {
  __shared__ float Sl[128 * 128];      // 64 KB (only j<=i used)
  __shared__ float Ycm[128 * 134];     // 67 KB, Ycm[c][j] = Y[j][c]
  __shared__ float invd[128];
  __shared__ float accl[8 * 128];
  const int tid = threadIdx.x;
  for (int idx = tid; idx < 16384; idx += 256) Sl[idx] = S_raw[idx];
  __syncthreads();
  if (tid < 128) {
    float d = Sl[tid * 128 + tid];
    float sp = (d > 20.f) ? d : log1pf(expf(d));
    invd[tid] = 1.f / (sp + 1e-3f);
  }
  __syncthreads();
  const int c = tid & 127, rh = tid >> 7;    // 2 halves x 4 rows each
  for (int bi = 0; bi < 16; ++bi) {
    const int J = bi * 8;
    float acc4[4] = {0.f, 0.f, 0.f, 0.f};
    for (int j = 0; j < J; j += 2) {
      float2 yv = *(const float2*)&Ycm[c * 134 + j];
      #pragma unroll
      for (int k = 0; k < 4; ++k) {
        float2 sv = *(const float2*)&Sl[(J + rh * 4 + k) * 128 + j];  // broadcast
        acc4[k] += sv.x * yv.x + sv.y * yv.y;
      }
    }
    #pragma unroll
    for (int k = 0; k < 4; ++k) accl[(rh * 4 + k) * 128 + c] = acc4[k];
    __syncthreads();
    if (tid < 128) {
      float a8[8], y8[8];
      #pragma unroll
      for (int qq = 0; qq < 8; ++qq) a8[qq] = accl[qq * 128 + c];
      #pragma unroll
      for (int qq = 0; qq < 8; ++qq) {
        float s = ((c == J + qq) ? 1.f : 0.f) - a8[qq];
        #pragma unroll
        for (int p = 0; p < 8; ++p)
          if (p < qq) s -= Sl[(J + qq) * 128 + (J + p)] * y8[p];
        y8[qq] = s * invd[J + qq];
      }
      #pragma unroll
      for (int k = 0; k < 4; ++k)
        *(float2*)&Ycm[c * 134 + J + 2 * k] = make_float2(y8[2 * k], y8[2 * k + 1]);
    }
    __syncthreads();
  }
  for (int idx = tid; idx < 16384; idx += 256) {
    int i = idx >> 7, j = idx & 127;
    Sinvh[idx] = f2h(Ycm[j * 134 + i]);      // transpose back to [i][j]
  }
}

// ---------------------------------------------------------------------------
// pi: softmax(gelu(u@gw1^T+gb1)@gw2^T+gb2). 512 blocks x 256 thr, 128 pos/blk.
// ---------------------------------------------------------------------------
__global__ void __launch_bounds__(256) pi_kernel(
    const float* __restrict__ u, const float* __restrict__ gw1,
    const float* __restrict__ gb1, const float* __restrict__ gw2,
    const float* __restrict__ gb2, float* __restrict__ pi) {
  __shared__ float gw1t[64 * 64];   // [n][l]
  __shared__ float gw2t[64 * 8];    // [l][m]
  __shared__ float gb1s[64];
  __shared__ float gb2s[8];
  __shared__ float us[4][64], hs[4][64];
  const int tid = threadIdx.x;
  for (int idx = tid; idx < 4096; idx += 256) {
    int l = idx >> 6, n = idx & 63;
    gw1t[n * 64 + l] = gw1[idx];
  }
  for (int idx = tid; idx < 512; idx += 256) {
    int m = idx >> 6, l = idx & 63;
    gw2t[l * 8 + m] = gw2[idx];
  }
  if (tid < 64) gb1s[tid] = gb1[tid];
  if (tid < 8) gb2s[tid] = gb2[tid];
  __syncthreads();
  const int wv = tid >> 6, ln = tid & 63;
  const int pbase = blockIdx.x * 128;
  for (int it = 0; it < 32; ++it) {
    const int p = pbase + it * 4 + wv;
    us[wv][ln] = u[p * 64 + ln];
    __syncthreads();
    float a = gb1s[ln];
    #pragma unroll 8
    for (int n = 0; n < 64; ++n) a += gw1t[n * 64 + ln] * us[wv][n];
    hs[wv][ln] = 0.5f * a * (1.0f + erff(a * 0.70710678118654752f));
    __syncthreads();
    if (ln < 8) {
      float lg = gb2s[ln];
      #pragma unroll 8
      for (int l = 0; l < 64; ++l) lg += gw2t[l * 8 + ln] * hs[wv][l];
      float mx = lg;
      for (int d = 1; d < 8; d <<= 1) mx = fmaxf(mx, __shfl_xor(mx, d, 64));
      float e = expf(lg - mx);
      float sm = e;
      for (int d = 1; d < 8; d <<= 1) sm += __shfl_xor(sm, d, 64);
      pi[p * 8 + ln] = e / sm;
    }
    __syncthreads();
  }
}

// ---------------------------------------------------------------------------
// uc (MFMA): uc[p][a] = sum_{k=n*8+m} Kuqw[a][k] * (g u[p][n] pi[p][m]).
// M=128 (8 waves x 16 rows, A in 64 VGPR/lane), K=512, 16-pos tiles.
// ---------------------------------------------------------------------------
__global__ void __launch_bounds__(512) uc_kernel(
    const float* __restrict__ u, const float* __restrict__ pi,
    const float* __restrict__ lgam, const unsigned short* __restrict__ Kuqw,
    unsigned short* __restrict__ uc) {
  __shared__ __align__(16) unsigned short q[16][520];
  __shared__ float us[16][68];
  __shared__ float ps[16][9];
  const int tid = threadIdx.x;
  const int w = tid >> 6, l = tid & 63, arow = l & 15, lg = l >> 4;
  const int p0 = blockIdx.x * 128;
  const float g = expf(lgam[0]);
  uint4 A[16];
  {
    const uint4* Ag = (const uint4*)(Kuqw + (size_t)(16 * w + arow) * 512);
    #pragma unroll
    for (int kt = 0; kt < 16; ++kt) A[kt] = Ag[kt * 4 + lg];
  }
  const int bcol = tid & 15, sub = tid >> 4;
  for (int tile = 0; tile < 8; ++tile) {
    const int pb = p0 + tile * 16;
    {
      const int pos = tid >> 5, np = tid & 31;
      float2 uv = *(const float2*)&u[(size_t)(pb + pos) * 64 + np * 2];
      us[pos][np * 2]     = g * uv.x;
      us[pos][np * 2 + 1] = g * uv.y;
      if (tid < 128) ps[tid >> 3][tid & 7] = pi[(size_t)(pb + (tid >> 3)) * 8 + (tid & 7)];
    }
    __syncthreads();
    {
      float u0 = us[bcol][2 * sub], u1 = us[bcol][2 * sub + 1];
      unsigned short tmp[16];
      #pragma unroll
      for (int m = 0; m < 8; ++m) {
        float pm = ps[bcol][m];
        tmp[m]     = f2h(u0 * pm);
        tmp[8 + m] = f2h(u1 * pm);
      }
      uint4* dst = (uint4*)&q[bcol][sub * 16];
      dst[0] = *(uint4*)&tmp[0];
      dst[1] = *(uint4*)&tmp[8];
    }
    __syncthreads();
    f32x4 acc = {0.f, 0.f, 0.f, 0.f};
    #pragma unroll
    for (int kt = 0; kt < 16; ++kt) {
      uint4 bf = *(const uint4*)&q[arow][kt * 32 + lg * 8];
      acc = mfma16(A[kt], bf, acc);
    }
    {
      uint2 zp;
      zp.x = (unsigned)f2h(acc[0]) | ((unsigned)f2h(acc[1]) << 16);
      zp.y = (unsigned)f2h(acc[2]) | ((unsigned)f2h(acc[3]) << 16);
      *(uint2*)&uc[(size_t)(pb + arow) * 128 + 16 * w + lg * 4] = zp;
    }
    __syncthreads();
  }
}

// ---------------------------------------------------------------------------
// scan (MFMA): z_{t+1} = sum_m A_m (pi_m z_t) + uc_t, 16 batches/block.
// ---------------------------------------------------------------------------
static constexpr int LCH = 16, WBURN = 24;

__global__ void __launch_bounds__(512, 2) scan_kernel(
    const float* __restrict__ pi, const unsigned short* __restrict__ uc,
    const unsigned short* __restrict__ Ah, unsigned short* __restrict__ zbuf) {
  const int c = blockIdx.x >> 2, bg = blockIdx.x & 3;
  const int tid = threadIdx.x;
  const int w = tid >> 6, l = tid & 63, lb = l & 15, lg = l >> 4;
  const int tstore = c * LCH;
  int t0 = tstore - WBURN; if (t0 < 0) t0 = 0;
  const int tend = tstore + LCH;
  const int b0 = bg * 16;
  __shared__ __align__(16) unsigned short Zh[17 * 16 * 136];
  __shared__ __align__(16) unsigned short uc_lds[16 * 132];
  __shared__ float pi_lds[16 * 9];
  uint4 A[8][4];
  {
    const uint4* Ag = (const uint4*)Ah;
    const int rbase = (w * 16 + lb) * 16 + lg;
    #pragma unroll
    for (int m = 0; m < 8; ++m)
      #pragma unroll
      for (int kt = 0; kt < 4; ++kt)
        A[m][kt] = Ag[m * 2048 + rbase + kt * 4];
  }
  for (int i = tid; i < 2176; i += 512) { Zh[i] = 0; Zh[16 * 2176 + i] = 0; }
  {
    const int sb = tid >> 5, sj = (tid & 31) * 4;
    *(uint2*)&uc_lds[sb * 132 + sj] = *(const uint2*)&uc[((size_t)(b0 + sb) * TT + t0) * 128 + sj];
    if (tid < 128)
      pi_lds[(tid >> 3) * 9 + (tid & 7)] = pi[((size_t)(b0 + (tid >> 3)) * TT + t0) * 8 + (tid & 7)];
  }
  __syncthreads();
  const int row0 = w * 16 + lg * 4;
  for (int t = t0; t < tend; ++t) {
    const int t1 = t + 1;
    const int islot = (t  < tstore) ? 16 : (t  - tstore);
    const int oslot = (t1 < tstore) ? 16 : (t1 - tstore);
    const bool hv = (t1 < tend);
    const int sb = tid >> 5, sj = (tid & 31) * 4;
    uint2 ucn = make_uint2(0u, 0u);
    float pin = 0.f;
    if (hv) {
      ucn = *(const uint2*)&uc[((size_t)(b0 + sb) * TT + t1) * 128 + sj];
      if (tid < 128) pin = pi[((size_t)(b0 + (tid >> 3)) * TT + t1) * 8 + (tid & 7)];
    }
    uint4 zf[4];
    const unsigned short* zb = &Zh[islot * 2176 + lb * 136 + lg * 8];
    #pragma unroll
    for (int kt = 0; kt < 4; ++kt) zf[kt] = *(const uint4*)&zb[kt * 32];
    h1 pih[8];
    #pragma unroll
    for (int m = 0; m < 8; ++m) pih[m] = (h1)pi_lds[lb * 9 + m];
    f32x4 acc[4];
    #pragma unroll
    for (int qq = 0; qq < 4; ++qq) acc[qq] = (f32x4){0.f, 0.f, 0.f, 0.f};
    #pragma unroll
    for (int m = 0; m < 8; ++m) {
      #pragma unroll
      for (int kt = 0; kt < 4; ++kt) {
        f16x8 bf = __builtin_bit_cast(f16x8, zf[kt]) * pih[m];
        acc[m & 3] = __builtin_amdgcn_mfma_f32_16x16x32_f16(
            __builtin_bit_cast(f16x8, A[m][kt]), bf, acc[m & 3], 0, 0, 0);
      }
    }
    unsigned short zh4[4];
    #pragma unroll
    for (int rr = 0; rr < 4; ++rr) {
      float s = acc[0][rr] + acc[1][rr] + acc[2][rr] + acc[3][rr];
      s += h2f(uc_lds[lb * 132 + row0 + rr]);
      zh4[rr] = f2h(s);
    }
    __syncthreads();
    {
      uint2 zp;
      zp.x = (unsigned)zh4[0] | ((unsigned)zh4[1] << 16);
      zp.y = (unsigned)zh4[2] | ((unsigned)zh4[3] << 16);
      *(uint2*)&Zh[oslot * 2176 + lb * 136 + row0] = zp;
    }
    if (hv) {
      *(uint2*)&uc_lds[sb * 132 + sj] = ucn;
      if (tid < 128) pi_lds[(tid >> 3) * 9 + (tid & 7)] = pin;
    }
    __syncthreads();
  }
  {
    const int pair = tid >> 1, qq = tid & 1, s = pair >> 4, bb2 = pair & 15;
    const unsigned short* src = &Zh[s * 2176 + bb2 * 136 + qq * 64];
    unsigned short* dst = &zbuf[((size_t)(b0 + bb2) * TT + tstore + s) * 128 + qq * 64];
    #pragma unroll
    for (int k = 0; k < 8; ++k) ((uint4*)dst)[k] = ((const uint4*)src)[k];
  }
}

// ---------------------------------------------------------------------------
// y (MFMA): y[p][ay] = sum_{k=n*8+m} Cw[ay][k] * (z[p][n] pi[p][m]).
// ---------------------------------------------------------------------------
__global__ void __launch_bounds__(256) y_kernel(
    const float* __restrict__ pi, const unsigned short* __restrict__ zbuf,
    const unsigned short* __restrict__ Cw, float* __restrict__ yout) {
  __shared__ __align__(16) unsigned short q[16][1032];
  __shared__ __align__(16) unsigned short zs[16][136];
  __shared__ float ps[16][9];
  const int tid = threadIdx.x;
  const int w = tid >> 6, l = tid & 63, arow = l & 15, lg = l >> 4;
  const int p0 = blockIdx.x * 128;
  uint4 A[32];
  {
    const uint4* Ag = (const uint4*)(Cw + (size_t)(16 * w + arow) * 1024);
    #pragma unroll
    for (int kt = 0; kt < 32; ++kt) A[kt] = Ag[kt * 4 + lg];
  }
  const int bcol = tid & 15, sub = tid >> 4;
  for (int tile = 0; tile < 8; ++tile) {
    const int pb = p0 + tile * 16;
    {
      const int pos = tid >> 4, seg = tid & 15;
      *(uint4*)&zs[pos][seg * 8] = *(const uint4*)&zbuf[(size_t)(pb + pos) * 128 + seg * 8];
      if (tid < 128) ps[tid >> 3][tid & 7] = pi[(size_t)(pb + (tid >> 3)) * 8 + (tid & 7)];
    }
    __syncthreads();
    {
      unsigned short zarr[8];
      *(uint4*)zarr = *(const uint4*)&zs[bcol][sub * 8];
      float pm[8];
      #pragma unroll
      for (int m = 0; m < 8; ++m) pm[m] = ps[bcol][m];
      #pragma unroll
      for (int nn = 0; nn < 8; ++nn) {
        float zf = h2f(zarr[nn]);
        unsigned short tmp[8];
        #pragma unroll
        for (int m = 0; m < 8; ++m) tmp[m] = f2h(zf * pm[m]);
        *(uint4*)&q[bcol][sub * 64 + nn * 8] = *(uint4*)tmp;
      }
    }
    __syncthreads();
    f32x4 acc = {0.f, 0.f, 0.f, 0.f};
    #pragma unroll
    for (int kt = 0; kt < 32; ++kt) {
      uint4 bf = *(const uint4*)&q[arow][kt * 32 + lg * 8];
      acc = mfma16(A[kt], bf, acc);
    }
    *(f32x4*)&yout[(size_t)(pb + arow) * 64 + 16 * w + lg * 4] = acc;
    __syncthreads();
  }
}

// ---------------------------------------------------------------------------
// x (MFMA): x[p][i] = sum_j Sinv[i][j] z[p][j].  M=128 (8 waves), K=128.
// ---------------------------------------------------------------------------
__global__ void __launch_bounds__(512) x_kernel(
    const unsigned short* __restrict__ zbuf, const unsigned short* __restrict__ Sinvh,
    float* __restrict__ xout) {
  const int tid = threadIdx.x;
  const int w = tid >> 6, l = tid & 63, arow = l & 15, lg = l >> 4;
  const int p0 = blockIdx.x * 128;
  uint4 A[4];
  {
    const uint4* Ag = (const uint4*)(Sinvh + (size_t)(16 * w + arow) * 128);
    #pragma unroll
    for (int kt = 0; kt < 4; ++kt) A[kt] = Ag[kt * 4 + lg];
  }
  for (int tile = 0; tile < 8; ++tile) {
    const int pb = p0 + tile * 16;
    const uint4* Z = (const uint4*)(zbuf + (size_t)(pb + arow) * 128);
    f32x4 acc = {0.f, 0.f, 0.f, 0.f};
    #pragma unroll
    for (int kt = 0; kt < 4; ++kt) {
      acc = mfma16(A[kt], Z[kt * 4 + lg], acc);
    }
    *(f32x4*)&xout[(size_t)(pb + arow) * 128 + 16 * w + lg * 4] = acc;
  }
}

// ---------------------------------------------------------------------------
extern "C" void kernel_launch(void* const* d_in, const int* in_sizes, int n_in,
                              void* d_out, int out_size, void* d_ws, size_t ws_size,
                              hipStream_t stream) {
  const float* u      = (const float*)d_in[0];
  const float* K_raw  = (const float*)d_in[1];
  const float* lgam   = (const float*)d_in[2];
  const float* S_raw  = (const float*)d_in[3];
  const float* gw1    = (const float*)d_in[4];
  const float* gb1    = (const float*)d_in[5];
  const float* gw2    = (const float*)d_in[6];
  const float* gb2    = (const float*)d_in[7];

  char* w = (char*)d_ws;
  size_t off = 0;
  auto carve = [&](size_t bytes) -> void* {
    void* p = (void*)(w + off);
    off += (bytes + 255) & ~(size_t)255;
    return p;
  };
  float* pi            = (float*)carve((size_t)NPOS * 8 * 4);            // 2MB
  unsigned short* uc   = (unsigned short*)carve((size_t)NPOS * 128 * 2); // 16MB
  unsigned short* zbuf = (unsigned short*)carve((size_t)NPOS * 128 * 2); // 16MB
  unsigned short* Ah   = (unsigned short*)carve(8 * 128 * 128 * 2);
  unsigned short* Kuqw = (unsigned short*)carve(128 * 512 * 2);
  unsigned short* Cw   = (unsigned short*)carve(64 * 1024 * 2);
  unsigned short* Svh  = (unsigned short*)carve(128 * 128 * 2);

  float* yout = (float*)d_out;
  float* xout = yout + (size_t)NPOS * 64;

  prep_expert_kernel<<<dim3(8),   dim3(768), 0, stream>>>(K_raw, Ah, Kuqw, Cw);
  prep_sinv_kernel  <<<dim3(1),   dim3(256), 0, stream>>>(S_raw, Svh);
  pi_kernel  <<<dim3(512),  dim3(256),  0, stream>>>(u, gw1, gb1, gw2, gb2, pi);
  uc_kernel  <<<dim3(512),  dim3(512),  0, stream>>>(u, pi, lgam, Kuqw, uc);
  scan_kernel<<<dim3(256),  dim3(512),  0, stream>>>(pi, uc, Ah, zbuf);
  y_kernel   <<<dim3(512),  dim3(256),  0, stream>>>(pi, zbuf, Cw, yout);
  x_kernel   <<<dim3(512),  dim3(512),  0, stream>>>(zbuf, Svh, xout);
}

// Round 5
// 219.173 us; speedup vs baseline: 4.1961x; 1.2743x over previous
//
#include <hip/hip_runtime.h>
#include <math.h>

// ExpertSelectiveTimeVaryingSSM — MI355X
// prep_expert + prep_sinv -> pi (MFMA) -> uc (MFMA) -> scan (MFMA) -> y (MFMA) -> x (MFMA).
// Math: z_{t+1} = sum_m pi_m A_m z_t + uc_t ;  y_t = sum_m pi_m C_m z_t ;
//       x_t = S^-1 z_t.  Flattened k = n*8+m folds the pi-weighted expert sum
//       into plain GEMMs for uc and y.

static constexpr int BB = 64, TT = 1024;
static constexpr int NPOS = BB * TT;           // 65536

typedef _Float16 h1;
typedef _Float16 h2v  __attribute__((ext_vector_type(2)));
typedef _Float16 f16x8 __attribute__((ext_vector_type(8)));
typedef float    f32x4 __attribute__((ext_vector_type(4)));

__device__ __forceinline__ float fdot2(unsigned int a, unsigned int b, float c) {
  return __builtin_amdgcn_fdot2(__builtin_bit_cast(h2v, a), __builtin_bit_cast(h2v, b), c, false);
}
__device__ __forceinline__ unsigned short f2h(float x) {
  h1 h = (h1)x; return __builtin_bit_cast(unsigned short, h);
}
__device__ __forceinline__ float h2f(unsigned short x) {
  return (float)__builtin_bit_cast(h1, x);
}
__device__ __forceinline__ f32x4 mfma16(uint4 a, uint4 b, f32x4 c) {
  return __builtin_amdgcn_mfma_f32_16x16x32_f16(
      __builtin_bit_cast(f16x8, a), __builtin_bit_cast(f16x8, b), c, 0, 0, 0);
}

// ---------------------------------------------------------------------------
// prep_expert: 8 blocks x 768 thr.  Power iteration on K^T K with K and K^T
// both f16-staged in LDS (row stride 200 halves).  4 lanes/row fdot2 matvecs,
// no per-iter normalization (x2 scaling), Rayleigh quotient at the end.
// Outputs: Ah[m][a][n]; Kuqw[a][n*8+m] (K=512); Cw[ay][n*8+m] (K=1024).
// ---------------------------------------------------------------------------
__global__ void __launch_bounds__(768) prep_expert_kernel(
    const float* __restrict__ K_raw, unsigned short* __restrict__ Ah,
    unsigned short* __restrict__ Kuqw, unsigned short* __restrict__ Cw) {
  __shared__ __align__(16) unsigned short Kh[192 * 200];   // 76800 B
  __shared__ __align__(16) unsigned short KhT[192 * 200];  // 76800 B
  __shared__ __align__(16) unsigned short vh[200];
  __shared__ __align__(16) unsigned short wh[200];
  __shared__ float red[256];
  const int blk = blockIdx.x, tid = threadIdx.x;
  const float* K = K_raw + blk * 36864;
  for (int idx = tid; idx < 36864; idx += 768) {
    int r = idx / 192, n = idx - r * 192;
    float kv = K[idx];
    if (r >= 128 && n >= 128) kv = 0.f;      // zeroed u->y block
    unsigned short h = f2h(kv);
    Kh[r * 200 + n] = h;
    KhT[n * 200 + r] = h;
  }
  {
    const uint4 z4 = make_uint4(0u, 0u, 0u, 0u);
    for (int r = tid; r < 192; r += 768) {
      *(uint4*)&Kh[r * 200 + 192] = z4;
      *(uint4*)&KhT[r * 200 + 192] = z4;
    }
    if (tid < 8) { vh[192 + tid] = 0; wh[192 + tid] = 0; }
    if (tid < 192) vh[tid] = f2h(1.f);
  }
  __syncthreads();
  const int r = tid >> 2, q = tid & 3;       // 768 = 192 rows x 4 quarters
  auto matvec = [&](const unsigned short* M, const unsigned short* src,
                    unsigned short* dst) {
    float acc = 0.f;
    const uint4* Mr = (const uint4*)(M + r * 200 + 48 * q);
    const uint4* Vv = (const uint4*)(src + 48 * q);
    #pragma unroll
    for (int j = 0; j < 6; ++j) {
      uint4 mv = Mr[j], sv = Vv[j];
      acc = fdot2(mv.x, sv.x, acc);
      acc = fdot2(mv.y, sv.y, acc);
      acc = fdot2(mv.z, sv.z, acc);
      acc = fdot2(mv.w, sv.w, acc);
    }
    acc += __shfl_xor(acc, 1, 64);
    acc += __shfl_xor(acc, 2, 64);
    if (q == 0) dst[r] = f2h(2.f * acc);     // x2 keeps f16 range w/o renorm
  };
  for (int it = 0; it < 9; ++it) {
    matvec(Kh, vh, wh);  __syncthreads();
    matvec(KhT, wh, vh); __syncthreads();
  }
  matvec(Kh, vh, wh);  __syncthreads();      // final half-step: w = 2 K v
  float aw = (tid < 192) ? h2f(wh[tid]) : 0.f;
  float av = (tid < 192) ? h2f(vh[tid]) : 0.f;
  if (tid < 256) red[tid] = aw * aw;
  __syncthreads();
  for (int st = 128; st > 0; st >>= 1) { if (tid < st) red[tid] += red[tid + st]; __syncthreads(); }
  const float nw2 = red[0];
  __syncthreads();
  if (tid < 256) red[tid] = av * av;
  __syncthreads();
  for (int st = 128; st > 0; st >>= 1) { if (tid < st) red[tid] += red[tid + st]; __syncthreads(); }
  const float nv2 = red[0];
  const float sigma = sqrtf(nw2 / (4.f * nv2 + 1e-30f));   // ||Kv||/||v||
  const float inv = (sigma > 1.f) ? 1.f / sigma : 1.f;
  __syncthreads();
  for (int idx = tid; idx < 16384; idx += 768) {       // Ah: [m][a][n]
    int a = idx >> 7, n = idx & 127;
    Ah[blk * 16384 + idx] = f2h(h2f(Kh[a * 200 + n]) * inv);
  }
  for (int idx = tid; idx < 8192; idx += 768) {        // Kuqw: [a][n*8+m]
    int a = idx >> 6, n = idx & 63;
    Kuqw[a * 512 + n * 8 + blk] = f2h(h2f(Kh[a * 200 + 128 + n]) * inv);
  }
  for (int idx = tid; idx < 8192; idx += 768) {        // Cw: [ay][n*8+m]
    int ay = idx >> 7, n = idx & 127;
    Cw[ay * 1024 + n * 8 + blk] = f2h(h2f(Kh[(128 + ay) * 200 + n]) * inv);
  }
}

// ---------------------------------------------------------------------------
// prep_sinv: 1 block x 256 thr.  Blocked forward substitution (BS=8).
// ---------------------------------------------------------------------------
__global__ void __launch_bounds__(256) prep_sinv_kernel(
    const float* __restrict__ S_raw, unsigned short* __restrict__ Sinvh) {
  __shared__ float Sl[128 * 128];      // 64 KB (only j<=i used)
  __shared__ float Ycm[128 * 134];     // Ycm[c][j] = Y[j][c]
  __shared__ float invd[128];
  __shared__ float accl[8 * 128];
  const int tid = threadIdx.x;
  for (int idx = tid; idx < 16384; idx += 256) Sl[idx] = S_raw[idx];
  __syncthreads();
  if (tid < 128) {
    float d = Sl[tid * 128 + tid];
    float sp = (d > 20.f) ? d : log1pf(expf(d));
    invd[tid] = 1.f / (sp + 1e-3f);
  }
  __syncthreads();
  const int c = tid & 127, rh = tid >> 7;    // 2 halves x 4 rows each
  for (int bi = 0; bi < 16; ++bi) {
    const int J = bi * 8;
    float acc4[4] = {0.f, 0.f, 0.f, 0.f};
    for (int j = 0; j < J; j += 2) {
      float2 yv = *(const float2*)&Ycm[c * 134 + j];
      #pragma unroll
      for (int k = 0; k < 4; ++k) {
        float2 sv = *(const float2*)&Sl[(J + rh * 4 + k) * 128 + j];  // broadcast
        acc4[k] += sv.x * yv.x + sv.y * yv.y;
      }
    }
    #pragma unroll
    for (int k = 0; k < 4; ++k) accl[(rh * 4 + k) * 128 + c] = acc4[k];
    __syncthreads();
    if (tid < 128) {
      float a8[8], y8[8];
      #pragma unroll
      for (int qq = 0; qq < 8; ++qq) a8[qq] = accl[qq * 128 + c];
      #pragma unroll
      for (int qq = 0; qq < 8; ++qq) {
        float s = ((c == J + qq) ? 1.f : 0.f) - a8[qq];
        #pragma unroll
        for (int p = 0; p < 8; ++p)
          if (p < qq) s -= Sl[(J + qq) * 128 + (J + p)] * y8[p];
        y8[qq] = s * invd[J + qq];
      }
      #pragma unroll
      for (int k = 0; k < 4; ++k)
        *(float2*)&Ycm[c * 134 + J + 2 * k] = make_float2(y8[2 * k], y8[2 * k + 1]);
    }
    __syncthreads();
  }
  for (int idx = tid; idx < 16384; idx += 256) {
    int i = idx >> 7, j = idx & 127;
    Sinvh[idx] = f2h(Ycm[j * 134 + i]);      // transpose back to [i][j]
  }
}

// ---------------------------------------------------------------------------
// pi (MFMA): h = gelu(u@gw1^T+gb1) [2 MFMA/wave/tile], logits = h@gw2^T+gb2
// [2 MFMA, gw2 zero-padded 8->16 rows], softmax via one shfl_xor(16) pair.
// 1024 blocks x 256 thr (4 waves), 64 pos/block (4 tiles of 16).
// ---------------------------------------------------------------------------
__global__ void __launch_bounds__(256) pi_kernel(
    const float* __restrict__ u, const float* __restrict__ gw1,
    const float* __restrict__ gb1, const float* __restrict__ gw2,
    const float* __restrict__ gb2, float* __restrict__ pi) {
  __shared__ __align__(16) unsigned short h_lds[4][16][72];   // 9216 B
  const int tid = threadIdx.x;
  const int w = tid >> 6, l = tid & 63, arow = l & 15, lg = l >> 4;
  const int p0 = blockIdx.x * 64;
  uint4 Agw1[2], Agw2[2];
  #pragma unroll
  for (int kt = 0; kt < 2; ++kt) {                 // gw1 rows 16w+arow
    const float* src = gw1 + (size_t)(16 * w + arow) * 64 + kt * 32 + lg * 8;
    unsigned short tmp[8];
    #pragma unroll
    for (int j = 0; j < 8; ++j) tmp[j] = f2h(src[j]);
    Agw1[kt] = *(uint4*)tmp;
  }
  #pragma unroll
  for (int kt = 0; kt < 2; ++kt) {                 // gw2 rows arow (<8), else 0
    unsigned short tmp[8];
    if (arow < 8) {
      const float* src = gw2 + (size_t)arow * 64 + kt * 32 + lg * 8;
      #pragma unroll
      for (int j = 0; j < 8; ++j) tmp[j] = f2h(src[j]);
    } else {
      #pragma unroll
      for (int j = 0; j < 8; ++j) tmp[j] = 0;
    }
    Agw2[kt] = *(uint4*)tmp;
  }
  float gb1v[4];
  #pragma unroll
  for (int rr = 0; rr < 4; ++rr) gb1v[rr] = gb1[16 * w + lg * 4 + rr];
  // phase 1: h tiles (each wave computes its 16 h-rows for all 4 tiles)
  #pragma unroll
  for (int tt = 0; tt < 4; ++tt) {
    const int pb = p0 + tt * 16;
    uint4 B[2];
    #pragma unroll
    for (int kt = 0; kt < 2; ++kt) {
      const float* src = u + (size_t)(pb + arow) * 64 + kt * 32 + lg * 8;
      unsigned short tmp[8];
      #pragma unroll
      for (int j = 0; j < 8; ++j) tmp[j] = f2h(src[j]);
      B[kt] = *(uint4*)tmp;
    }
    f32x4 acc = {0.f, 0.f, 0.f, 0.f};
    acc = mfma16(Agw1[0], B[0], acc);
    acc = mfma16(Agw1[1], B[1], acc);
    unsigned short hh[4];
    #pragma unroll
    for (int rr = 0; rr < 4; ++rr) {
      float a = acc[rr] + gb1v[rr];
      float gel = 0.5f * a * (1.0f + erff(a * 0.70710678118654752f));
      hh[rr] = f2h(gel);
    }
    *(uint2*)&h_lds[tt][arow][16 * w + lg * 4] = *(uint2*)hh;
  }
  __syncthreads();
  // phase 2: wave w -> tile w.  logits col=arow(pos), row=lg*4+r (valid lg<2)
  {
    const int pb = p0 + w * 16;
    uint4 B0 = *(const uint4*)&h_lds[w][arow][lg * 8];
    uint4 B1 = *(const uint4*)&h_lds[w][arow][32 + lg * 8];
    f32x4 acc = {0.f, 0.f, 0.f, 0.f};
    acc = mfma16(Agw2[0], B0, acc);
    acc = mfma16(Agw2[1], B1, acc);
    float lo[4];
    #pragma unroll
    for (int rr = 0; rr < 4; ++rr)
      lo[rr] = acc[rr] + ((lg < 2) ? gb2[lg * 4 + rr] : 0.f);
    float mx = fmaxf(fmaxf(lo[0], lo[1]), fmaxf(lo[2], lo[3]));
    mx = fmaxf(mx, __shfl_xor(mx, 16, 64));
    float e[4];
    float ssum = 0.f;
    #pragma unroll
    for (int rr = 0; rr < 4; ++rr) { e[rr] = expf(lo[rr] - mx); ssum += e[rr]; }
    float tot = ssum + __shfl_xor(ssum, 16, 64);
    float invt = 1.f / tot;
    if (lg < 2) {
      float4 outv = make_float4(e[0] * invt, e[1] * invt, e[2] * invt, e[3] * invt);
      *(float4*)&pi[(size_t)(pb + arow) * 8 + lg * 4] = outv;
    }
  }
}

// ---------------------------------------------------------------------------
// uc (MFMA): uc[p][a] = sum_{k=n*8+m} Kuqw[a][k] * (g u[p][n] pi[p][m]).
// M=128 (8 waves x 16 rows, A in 64 VGPR/lane), K=512, 16-pos tiles.
// ---------------------------------------------------------------------------
__global__ void __launch_bounds__(512) uc_kernel(
    const float* __restrict__ u, const float* __restrict__ pi,
    const float* __restrict__ lgam, const unsigned short* __restrict__ Kuqw,
    unsigned short* __restrict__ uc) {
  __shared__ __align__(16) unsigned short q[16][520];
  __shared__ float us[16][68];
  __shared__ float ps[16][9];
  const int tid = threadIdx.x;
  const int w = tid >> 6, l = tid & 63, arow = l & 15, lg = l >> 4;
  const int p0 = blockIdx.x * 128;
  const float g = expf(lgam[0]);
  uint4 A[16];
  {
    const uint4* Ag = (const uint4*)(Kuqw + (size_t)(16 * w + arow) * 512);
    #pragma unroll
    for (int kt = 0; kt < 16; ++kt) A[kt] = Ag[kt * 4 + lg];
  }
  const int bcol = tid & 15, sub = tid >> 4;
  for (int tile = 0; tile < 8; ++tile) {
    const int pb = p0 + tile * 16;
    {
      const int pos = tid >> 5, np = tid & 31;
      float2 uv = *(const float2*)&u[(size_t)(pb + pos) * 64 + np * 2];
      us[pos][np * 2]     = g * uv.x;
      us[pos][np * 2 + 1] = g * uv.y;
      if (tid < 128) ps[tid >> 3][tid & 7] = pi[(size_t)(pb + (tid >> 3)) * 8 + (tid & 7)];
    }
    __syncthreads();
    {
      float u0 = us[bcol][2 * sub], u1 = us[bcol][2 * sub + 1];
      unsigned short tmp[16];
      #pragma unroll
      for (int m = 0; m < 8; ++m) {
        float pm = ps[bcol][m];
        tmp[m]     = f2h(u0 * pm);
        tmp[8 + m] = f2h(u1 * pm);
      }
      uint4* dst = (uint4*)&q[bcol][sub * 16];
      dst[0] = *(uint4*)&tmp[0];
      dst[1] = *(uint4*)&tmp[8];
    }
    __syncthreads();
    f32x4 acc = {0.f, 0.f, 0.f, 0.f};
    #pragma unroll
    for (int kt = 0; kt < 16; ++kt) {
      uint4 bf = *(const uint4*)&q[arow][kt * 32 + lg * 8];
      acc = mfma16(A[kt], bf, acc);
    }
    {
      uint2 zp;
      zp.x = (unsigned)f2h(acc[0]) | ((unsigned)f2h(acc[1]) << 16);
      zp.y = (unsigned)f2h(acc[2]) | ((unsigned)f2h(acc[3]) << 16);
      *(uint2*)&uc[(size_t)(pb + arow) * 128 + 16 * w + lg * 4] = zp;
    }
    __syncthreads();
  }
}

// ---------------------------------------------------------------------------
// scan (MFMA): z_{t+1} = sum_m A_m (pi_m z_t) + uc_t, 16 batches/block.
// ---------------------------------------------------------------------------
static constexpr int LCH = 16, WBURN = 24;

__global__ void __launch_bounds__(512, 2) scan_kernel(
    const float* __restrict__ pi, const unsigned short* __restrict__ uc,
    const unsigned short* __restrict__ Ah, unsigned short* __restrict__ zbuf) {
  const int c = blockIdx.x >> 2, bg = blockIdx.x & 3;
  const int tid = threadIdx.x;
  const int w = tid >> 6, l = tid & 63, lb = l & 15, lg = l >> 4;
  const int tstore = c * LCH;
  int t0 = tstore - WBURN; if (t0 < 0) t0 = 0;
  const int tend = tstore + LCH;
  const int b0 = bg * 16;
  __shared__ __align__(16) unsigned short Zh[17 * 16 * 136];
  __shared__ __align__(16) unsigned short uc_lds[16 * 132];
  __shared__ float pi_lds[16 * 9];
  uint4 A[8][4];
  {
    const uint4* Ag = (const uint4*)Ah;
    const int rbase = (w * 16 + lb) * 16 + lg;
    #pragma unroll
    for (int m = 0; m < 8; ++m)
      #pragma unroll
      for (int kt = 0; kt < 4; ++kt)
        A[m][kt] = Ag[m * 2048 + rbase + kt * 4];
  }
  for (int i = tid; i < 2176; i += 512) { Zh[i] = 0; Zh[16 * 2176 + i] = 0; }
  {
    const int sb = tid >> 5, sj = (tid & 31) * 4;
    *(uint2*)&uc_lds[sb * 132 + sj] = *(const uint2*)&uc[((size_t)(b0 + sb) * TT + t0) * 128 + sj];
    if (tid < 128)
      pi_lds[(tid >> 3) * 9 + (tid & 7)] = pi[((size_t)(b0 + (tid >> 3)) * TT + t0) * 8 + (tid & 7)];
  }
  __syncthreads();
  const int row0 = w * 16 + lg * 4;
  for (int t = t0; t < tend; ++t) {
    const int t1 = t + 1;
    const int islot = (t  < tstore) ? 16 : (t  - tstore);
    const int oslot = (t1 < tstore) ? 16 : (t1 - tstore);
    const bool hv = (t1 < tend);
    const int sb = tid >> 5, sj = (tid & 31) * 4;
    uint2 ucn = make_uint2(0u, 0u);
    float pin = 0.f;
    if (hv) {
      ucn = *(const uint2*)&uc[((size_t)(b0 + sb) * TT + t1) * 128 + sj];
      if (tid < 128) pin = pi[((size_t)(b0 + (tid >> 3)) * TT + t1) * 8 + (tid & 7)];
    }
    uint4 zf[4];
    const unsigned short* zb = &Zh[islot * 2176 + lb * 136 + lg * 8];
    #pragma unroll
    for (int kt = 0; kt < 4; ++kt) zf[kt] = *(const uint4*)&zb[kt * 32];
    h1 pih[8];
    #pragma unroll
    for (int m = 0; m < 8; ++m) pih[m] = (h1)pi_lds[lb * 9 + m];
    f32x4 acc[4];
    #pragma unroll
    for (int qq = 0; qq < 4; ++qq) acc[qq] = (f32x4){0.f, 0.f, 0.f, 0.f};
    #pragma unroll
    for (int m = 0; m < 8; ++m) {
      #pragma unroll
      for (int kt = 0; kt < 4; ++kt) {
        f16x8 bf = __builtin_bit_cast(f16x8, zf[kt]) * pih[m];
        acc[m & 3] = __builtin_amdgcn_mfma_f32_16x16x32_f16(
            __builtin_bit_cast(f16x8, A[m][kt]), bf, acc[m & 3], 0, 0, 0);
      }
    }
    unsigned short zh4[4];
    #pragma unroll
    for (int rr = 0; rr < 4; ++rr) {
      float s = acc[0][rr] + acc[1][rr] + acc[2][rr] + acc[3][rr];
      s += h2f(uc_lds[lb * 132 + row0 + rr]);
      zh4[rr] = f2h(s);
    }
    __syncthreads();
    {
      uint2 zp;
      zp.x = (unsigned)zh4[0] | ((unsigned)zh4[1] << 16);
      zp.y = (unsigned)zh4[2] | ((unsigned)zh4[3] << 16);
      *(uint2*)&Zh[oslot * 2176 + lb * 136 + row0] = zp;
    }
    if (hv) {
      *(uint2*)&uc_lds[sb * 132 + sj] = ucn;
      if (tid < 128) pi_lds[(tid >> 3) * 9 + (tid & 7)] = pin;
    }
    __syncthreads();
  }
  {
    const int pair = tid >> 1, qq = tid & 1, s = pair >> 4, bb2 = pair & 15;
    const unsigned short* src = &Zh[s * 2176 + bb2 * 136 + qq * 64];
    unsigned short* dst = &zbuf[((size_t)(b0 + bb2) * TT + tstore + s) * 128 + qq * 64];
    #pragma unroll
    for (int k = 0; k < 8; ++k) ((uint4*)dst)[k] = ((const uint4*)src)[k];
  }
}

// ---------------------------------------------------------------------------
// y (MFMA): y[p][ay] = sum_{k=n*8+m} Cw[ay][k] * (z[p][n] pi[p][m]).
// ---------------------------------------------------------------------------
__global__ void __launch_bounds__(256) y_kernel(
    const float* __restrict__ pi, const unsigned short* __restrict__ zbuf,
    const unsigned short* __restrict__ Cw, float* __restrict__ yout) {
  __shared__ __align__(16) unsigned short q[16][1032];
  __shared__ __align__(16) unsigned short zs[16][136];
  __shared__ float ps[16][9];
  const int tid = threadIdx.x;
  const int w = tid >> 6, l = tid & 63, arow = l & 15, lg = l >> 4;
  const int p0 = blockIdx.x * 128;
  uint4 A[32];
  {
    const uint4* Ag = (const uint4*)(Cw + (size_t)(16 * w + arow) * 1024);
    #pragma unroll
    for (int kt = 0; kt < 32; ++kt) A[kt] = Ag[kt * 4 + lg];
  }
  const int bcol = tid & 15, sub = tid >> 4;
  for (int tile = 0; tile < 8; ++tile) {
    const int pb = p0 + tile * 16;
    {
      const int pos = tid >> 4, seg = tid & 15;
      *(uint4*)&zs[pos][seg * 8] = *(const uint4*)&zbuf[(size_t)(pb + pos) * 128 + seg * 8];
      if (tid < 128) ps[tid >> 3][tid & 7] = pi[(size_t)(pb + (tid >> 3)) * 8 + (tid & 7)];
    }
    __syncthreads();
    {
      unsigned short zarr[8];
      *(uint4*)zarr = *(const uint4*)&zs[bcol][sub * 8];
      float pm[8];
      #pragma unroll
      for (int m = 0; m < 8; ++m) pm[m] = ps[bcol][m];
      #pragma unroll
      for (int nn = 0; nn < 8; ++nn) {
        float zf = h2f(zarr[nn]);
        unsigned short tmp[8];
        #pragma unroll
        for (int m = 0; m < 8; ++m) tmp[m] = f2h(zf * pm[m]);
        *(uint4*)&q[bcol][sub * 64 + nn * 8] = *(uint4*)tmp;
      }
    }
    __syncthreads();
    f32x4 acc = {0.f, 0.f, 0.f, 0.f};
    #pragma unroll
    for (int kt = 0; kt < 32; ++kt) {
      uint4 bf = *(const uint4*)&q[arow][kt * 32 + lg * 8];
      acc = mfma16(A[kt], bf, acc);
    }
    *(f32x4*)&yout[(size_t)(pb + arow) * 64 + 16 * w + lg * 4] = acc;
    __syncthreads();
  }
}

// ---------------------------------------------------------------------------
// x (MFMA): x[p][i] = sum_j Sinv[i][j] z[p][j].  M=128 (8 waves), K=128.
// ---------------------------------------------------------------------------
__global__ void __launch_bounds__(512) x_kernel(
    const unsigned short* __restrict__ zbuf, const unsigned short* __restrict__ Sinvh,
    float* __restrict__ xout) {
  const int tid = threadIdx.x;
  const int w = tid >> 6, l = tid & 63, arow = l & 15, lg = l >> 4;
  const int p0 = blockIdx.x * 128;
  uint4 A[4];
  {
    const uint4* Ag = (const uint4*)(Sinvh + (size_t)(16 * w + arow) * 128);
    #pragma unroll
    for (int kt = 0; kt < 4; ++kt) A[kt] = Ag[kt * 4 + lg];
  }
  for (int tile = 0; tile < 8; ++tile) {
    const int pb = p0 + tile * 16;
    const uint4* Z = (const uint4*)(zbuf + (size_t)(pb + arow) * 128);
    f32x4 acc = {0.f, 0.f, 0.f, 0.f};
    #pragma unroll
    for (int kt = 0; kt < 4; ++kt) {
      acc = mfma16(A[kt], Z[kt * 4 + lg], acc);
    }
    *(f32x4*)&xout[(size_t)(pb + arow) * 128 + 16 * w + lg * 4] = acc;
  }
}

// ---------------------------------------------------------------------------
extern "C" void kernel_launch(void* const* d_in, const int* in_sizes, int n_in,
                              void* d_out, int out_size, void* d_ws, size_t ws_size,
                              hipStream_t stream) {
  const float* u      = (const float*)d_in[0];
  const float* K_raw  = (const float*)d_in[1];
  const float* lgam   = (const float*)d_in[2];
  const float* S_raw  = (const float*)d_in[3];
  const float* gw1    = (const float*)d_in[4];
  const float* gb1    = (const float*)d_in[5];
  const float* gw2    = (const float*)d_in[6];
  const float* gb2    = (const float*)d_in[7];

  char* w = (char*)d_ws;
  size_t off = 0;
  auto carve = [&](size_t bytes) -> void* {
    void* p = (void*)(w + off);
    off += (bytes + 255) & ~(size_t)255;
    return p;
  };
  float* pi            = (float*)carve((size_t)NPOS * 8 * 4);            // 2MB
  unsigned short* uc   = (unsigned short*)carve((size_t)NPOS * 128 * 2); // 16MB
  unsigned short* zbuf = (unsigned short*)carve((size_t)NPOS * 128 * 2); // 16MB
  unsigned short* Ah   = (unsigned short*)carve(8 * 128 * 128 * 2);
  unsigned short* Kuqw = (unsigned short*)carve(128 * 512 * 2);
  unsigned short* Cw   = (unsigned short*)carve(64 * 1024 * 2);
  unsigned short* Svh  = (unsigned short*)carve(128 * 128 * 2);

  float* yout = (float*)d_out;
  float* xout = yout + (size_t)NPOS * 64;

  prep_expert_kernel<<<dim3(8),   dim3(768), 0, stream>>>(K_raw, Ah, Kuqw, Cw);
  prep_sinv_kernel  <<<dim3(1),   dim3(256), 0, stream>>>(S_raw, Svh);
  pi_kernel  <<<dim3(1024), dim3(256),  0, stream>>>(u, gw1, gb1, gw2, gb2, pi);
  uc_kernel  <<<dim3(512),  dim3(512),  0, stream>>>(u, pi, lgam, Kuqw, uc);
  scan_kernel<<<dim3(256),  dim3(512),  0, stream>>>(pi, uc, Ah, zbuf);
  y_kernel   <<<dim3(512),  dim3(256),  0, stream>>>(pi, zbuf, Cw, yout);
  x_kernel   <<<dim3(512),  dim3(512),  0, stream>>>(zbuf, Svh, xout);
}

// Round 6
// 206.897 us; speedup vs baseline: 4.4451x; 1.0593x over previous
//
#include <hip/hip_runtime.h>
#include <math.h>

// ExpertSelectiveTimeVaryingSSM — MI355X
// prep_expert + prep_sinv -> pi (MFMA) -> uc (MFMA) -> scan (MFMA, group-staged
// LDS pipeline) -> y (MFMA) -> x (MFMA).
// Math: z_{t+1} = sum_m pi_m A_m z_t + uc_t ;  y_t = sum_m pi_m C_m z_t ;
//       x_t = S^-1 z_t.  Flattened k = n*8+m folds the pi-weighted expert sum
//       into plain GEMMs for uc and y.

static constexpr int BB = 64, TT = 1024;
static constexpr int NPOS = BB * TT;           // 65536

typedef _Float16 h1;
typedef _Float16 h2v  __attribute__((ext_vector_type(2)));
typedef _Float16 f16x8 __attribute__((ext_vector_type(8)));
typedef float    f32x4 __attribute__((ext_vector_type(4)));

__device__ __forceinline__ float fdot2(unsigned int a, unsigned int b, float c) {
  return __builtin_amdgcn_fdot2(__builtin_bit_cast(h2v, a), __builtin_bit_cast(h2v, b), c, false);
}
__device__ __forceinline__ unsigned short f2h(float x) {
  h1 h = (h1)x; return __builtin_bit_cast(unsigned short, h);
}
__device__ __forceinline__ float h2f(unsigned short x) {
  return (float)__builtin_bit_cast(h1, x);
}
__device__ __forceinline__ f32x4 mfma16(uint4 a, uint4 b, f32x4 c) {
  return __builtin_amdgcn_mfma_f32_16x16x32_f16(
      __builtin_bit_cast(f16x8, a), __builtin_bit_cast(f16x8, b), c, 0, 0, 0);
}

// ---------------------------------------------------------------------------
// prep_expert: 8 blocks x 768 thr.  Power iteration on K^T K with K and K^T
// both f16-staged in LDS (row stride 200 halves).  4 lanes/row fdot2 matvecs,
// no per-iter normalization (x2 scaling), Rayleigh quotient at the end.
// Outputs: Ah[m][a][n]; Kuqw[a][n*8+m] (K=512); Cw[ay][n*8+m] (K=1024).
// ---------------------------------------------------------------------------
__global__ void __launch_bounds__(768) prep_expert_kernel(
    const float* __restrict__ K_raw, unsigned short* __restrict__ Ah,
    unsigned short* __restrict__ Kuqw, unsigned short* __restrict__ Cw) {
  __shared__ __align__(16) unsigned short Kh[192 * 200];   // 76800 B
  __shared__ __align__(16) unsigned short KhT[192 * 200];  // 76800 B
  __shared__ __align__(16) unsigned short vh[200];
  __shared__ __align__(16) unsigned short wh[200];
  __shared__ float red[256];
  const int blk = blockIdx.x, tid = threadIdx.x;
  const float* K = K_raw + blk * 36864;
  for (int idx = tid; idx < 36864; idx += 768) {
    int r = idx / 192, n = idx - r * 192;
    float kv = K[idx];
    if (r >= 128 && n >= 128) kv = 0.f;      // zeroed u->y block
    unsigned short h = f2h(kv);
    Kh[r * 200 + n] = h;
    KhT[n * 200 + r] = h;
  }
  {
    const uint4 z4 = make_uint4(0u, 0u, 0u, 0u);
    for (int r = tid; r < 192; r += 768) {
      *(uint4*)&Kh[r * 200 + 192] = z4;
      *(uint4*)&KhT[r * 200 + 192] = z4;
    }
    if (tid < 8) { vh[192 + tid] = 0; wh[192 + tid] = 0; }
    if (tid < 192) vh[tid] = f2h(1.f);
  }
  __syncthreads();
  const int r = tid >> 2, q = tid & 3;       // 768 = 192 rows x 4 quarters
  auto matvec = [&](const unsigned short* M, const unsigned short* src,
                    unsigned short* dst) {
    float acc = 0.f;
    const uint4* Mr = (const uint4*)(M + r * 200 + 48 * q);
    const uint4* Vv = (const uint4*)(src + 48 * q);
    #pragma unroll
    for (int j = 0; j < 6; ++j) {
      uint4 mv = Mr[j], sv = Vv[j];
      acc = fdot2(mv.x, sv.x, acc);
      acc = fdot2(mv.y, sv.y, acc);
      acc = fdot2(mv.z, sv.z, acc);
      acc = fdot2(mv.w, sv.w, acc);
    }
    acc += __shfl_xor(acc, 1, 64);
    acc += __shfl_xor(acc, 2, 64);
    if (q == 0) dst[r] = f2h(2.f * acc);     // x2 keeps f16 range w/o renorm
  };
  for (int it = 0; it < 9; ++it) {
    matvec(Kh, vh, wh);  __syncthreads();
    matvec(KhT, wh, vh); __syncthreads();
  }
  matvec(Kh, vh, wh);  __syncthreads();      // final half-step: w = 2 K v
  float aw = (tid < 192) ? h2f(wh[tid]) : 0.f;
  float av = (tid < 192) ? h2f(vh[tid]) : 0.f;
  if (tid < 256) red[tid] = aw * aw;
  __syncthreads();
  for (int st = 128; st > 0; st >>= 1) { if (tid < st) red[tid] += red[tid + st]; __syncthreads(); }
  const float nw2 = red[0];
  __syncthreads();
  if (tid < 256) red[tid] = av * av;
  __syncthreads();
  for (int st = 128; st > 0; st >>= 1) { if (tid < st) red[tid] += red[tid + st]; __syncthreads(); }
  const float nv2 = red[0];
  const float sigma = sqrtf(nw2 / (4.f * nv2 + 1e-30f));   // ||Kv||/||v||
  const float inv = (sigma > 1.f) ? 1.f / sigma : 1.f;
  __syncthreads();
  for (int idx = tid; idx < 16384; idx += 768) {       // Ah: [m][a][n]
    int a = idx >> 7, n = idx & 127;
    Ah[blk * 16384 + idx] = f2h(h2f(Kh[a * 200 + n]) * inv);
  }
  for (int idx = tid; idx < 8192; idx += 768) {        // Kuqw: [a][n*8+m]
    int a = idx >> 6, n = idx & 63;
    Kuqw[a * 512 + n * 8 + blk] = f2h(h2f(Kh[a * 200 + 128 + n]) * inv);
  }
  for (int idx = tid; idx < 8192; idx += 768) {        // Cw: [ay][n*8+m]
    int ay = idx >> 7, n = idx & 127;
    Cw[ay * 1024 + n * 8 + blk] = f2h(h2f(Kh[(128 + ay) * 200 + n]) * inv);
  }
}

// ---------------------------------------------------------------------------
// prep_sinv: 1 block x 256 thr.  Blocked forward substitution (BS=8).
// ---------------------------------------------------------------------------
__global__ void __launch_bounds__(256) prep_sinv_kernel(
    const float* __restrict__ S_raw, unsigned short* __restrict__ Sinvh) {
  __shared__ float Sl[128 * 128];      // 64 KB (only j<=i used)
  __shared__ float Ycm[128 * 134];     // Ycm[c][j] = Y[j][c]
  __shared__ float invd[128];
  __shared__ float accl[8 * 128];
  const int tid = threadIdx.x;
  for (int idx = tid; idx < 16384; idx += 256) Sl[idx] = S_raw[idx];
  __syncthreads();
  if (tid < 128) {
    float d = Sl[tid * 128 + tid];
    float sp = (d > 20.f) ? d : log1pf(expf(d));
    invd[tid] = 1.f / (sp + 1e-3f);
  }
  __syncthreads();
  const int c = tid & 127, rh = tid >> 7;    // 2 halves x 4 rows each
  for (int bi = 0; bi < 16; ++bi) {
    const int J = bi * 8;
    float acc4[4] = {0.f, 0.f, 0.f, 0.f};
    for (int j = 0; j < J; j += 2) {
      float2 yv = *(const float2*)&Ycm[c * 134 + j];
      #pragma unroll
      for (int k = 0; k < 4; ++k) {
        float2 sv = *(const float2*)&Sl[(J + rh * 4 + k) * 128 + j];  // broadcast
        acc4[k] += sv.x * yv.x + sv.y * yv.y;
      }
    }
    #pragma unroll
    for (int k = 0; k < 4; ++k) accl[(rh * 4 + k) * 128 + c] = acc4[k];
    __syncthreads();
    if (tid < 128) {
      float a8[8], y8[8];
      #pragma unroll
      for (int qq = 0; qq < 8; ++qq) a8[qq] = accl[qq * 128 + c];
      #pragma unroll
      for (int qq = 0; qq < 8; ++qq) {
        float s = ((c == J + qq) ? 1.f : 0.f) - a8[qq];
        #pragma unroll
        for (int p = 0; p < 8; ++p)
          if (p < qq) s -= Sl[(J + qq) * 128 + (J + p)] * y8[p];
        y8[qq] = s * invd[J + qq];
      }
      #pragma unroll
      for (int k = 0; k < 4; ++k)
        *(float2*)&Ycm[c * 134 + J + 2 * k] = make_float2(y8[2 * k], y8[2 * k + 1]);
    }
    __syncthreads();
  }
  for (int idx = tid; idx < 16384; idx += 256) {
    int i = idx >> 7, j = idx & 127;
    Sinvh[idx] = f2h(Ycm[j * 134 + i]);      // transpose back to [i][j]
  }
}

// ---------------------------------------------------------------------------
// pi (MFMA): h = gelu(u@gw1^T+gb1) [2 MFMA/wave/tile], logits = h@gw2^T+gb2
// [2 MFMA, gw2 zero-padded 8->16 rows], softmax via one shfl_xor(16) pair.
// 1024 blocks x 256 thr (4 waves), 64 pos/block (4 tiles of 16).
// ---------------------------------------------------------------------------
__global__ void __launch_bounds__(256) pi_kernel(
    const float* __restrict__ u, const float* __restrict__ gw1,
    const float* __restrict__ gb1, const float* __restrict__ gw2,
    const float* __restrict__ gb2, float* __restrict__ pi) {
  __shared__ __align__(16) unsigned short h_lds[4][16][72];   // 9216 B
  const int tid = threadIdx.x;
  const int w = tid >> 6, l = tid & 63, arow = l & 15, lg = l >> 4;
  const int p0 = blockIdx.x * 64;
  uint4 Agw1[2], Agw2[2];
  #pragma unroll
  for (int kt = 0; kt < 2; ++kt) {                 // gw1 rows 16w+arow
    const float* src = gw1 + (size_t)(16 * w + arow) * 64 + kt * 32 + lg * 8;
    unsigned short tmp[8];
    #pragma unroll
    for (int j = 0; j < 8; ++j) tmp[j] = f2h(src[j]);
    Agw1[kt] = *(uint4*)tmp;
  }
  #pragma unroll
  for (int kt = 0; kt < 2; ++kt) {                 // gw2 rows arow (<8), else 0
    unsigned short tmp[8];
    if (arow < 8) {
      const float* src = gw2 + (size_t)arow * 64 + kt * 32 + lg * 8;
      #pragma unroll
      for (int j = 0; j < 8; ++j) tmp[j] = f2h(src[j]);
    } else {
      #pragma unroll
      for (int j = 0; j < 8; ++j) tmp[j] = 0;
    }
    Agw2[kt] = *(uint4*)tmp;
  }
  float gb1v[4];
  #pragma unroll
  for (int rr = 0; rr < 4; ++rr) gb1v[rr] = gb1[16 * w + lg * 4 + rr];
  // phase 1: h tiles (each wave computes its 16 h-rows for all 4 tiles)
  #pragma unroll
  for (int tt = 0; tt < 4; ++tt) {
    const int pb = p0 + tt * 16;
    uint4 B[2];
    #pragma unroll
    for (int kt = 0; kt < 2; ++kt) {
      const float* src = u + (size_t)(pb + arow) * 64 + kt * 32 + lg * 8;
      unsigned short tmp[8];
      #pragma unroll
      for (int j = 0; j < 8; ++j) tmp[j] = f2h(src[j]);
      B[kt] = *(uint4*)tmp;
    }
    f32x4 acc = {0.f, 0.f, 0.f, 0.f};
    acc = mfma16(Agw1[0], B[0], acc);
    acc = mfma16(Agw1[1], B[1], acc);
    unsigned short hh[4];
    #pragma unroll
    for (int rr = 0; rr < 4; ++rr) {
      float a = acc[rr] + gb1v[rr];
      float gel = 0.5f * a * (1.0f + erff(a * 0.70710678118654752f));
      hh[rr] = f2h(gel);
    }
    *(uint2*)&h_lds[tt][arow][16 * w + lg * 4] = *(uint2*)hh;
  }
  __syncthreads();
  // phase 2: wave w -> tile w.  logits col=arow(pos), row=lg*4+r (valid lg<2)
  {
    const int pb = p0 + w * 16;
    uint4 B0 = *(const uint4*)&h_lds[w][arow][lg * 8];
    uint4 B1 = *(const uint4*)&h_lds[w][arow][32 + lg * 8];
    f32x4 acc = {0.f, 0.f, 0.f, 0.f};
    acc = mfma16(Agw2[0], B0, acc);
    acc = mfma16(Agw2[1], B1, acc);
    float lo[4];
    #pragma unroll
    for (int rr = 0; rr < 4; ++rr)
      lo[rr] = acc[rr] + ((lg < 2) ? gb2[lg * 4 + rr] : 0.f);
    float mx = fmaxf(fmaxf(lo[0], lo[1]), fmaxf(lo[2], lo[3]));
    mx = fmaxf(mx, __shfl_xor(mx, 16, 64));
    float e[4];
    float ssum = 0.f;
    #pragma unroll
    for (int rr = 0; rr < 4; ++rr) { e[rr] = expf(lo[rr] - mx); ssum += e[rr]; }
    float tot = ssum + __shfl_xor(ssum, 16, 64);
    float invt = 1.f / tot;
    if (lg < 2) {
      float4 outv = make_float4(e[0] * invt, e[1] * invt, e[2] * invt, e[3] * invt);
      *(float4*)&pi[(size_t)(pb + arow) * 8 + lg * 4] = outv;
    }
  }
}

// ---------------------------------------------------------------------------
// uc (MFMA): uc[p][a] = sum_{k=n*8+m} Kuqw[a][k] * (g u[p][n] pi[p][m]).
// M=128 (8 waves x 16 rows, A in 64 VGPR/lane), K=512, 16-pos tiles.
// ---------------------------------------------------------------------------
__global__ void __launch_bounds__(512) uc_kernel(
    const float* __restrict__ u, const float* __restrict__ pi,
    const float* __restrict__ lgam, const unsigned short* __restrict__ Kuqw,
    unsigned short* __restrict__ uc) {
  __shared__ __align__(16) unsigned short q[16][520];
  __shared__ float us[16][68];
  __shared__ float ps[16][9];
  const int tid = threadIdx.x;
  const int w = tid >> 6, l = tid & 63, arow = l & 15, lg = l >> 4;
  const int p0 = blockIdx.x * 128;
  const float g = expf(lgam[0]);
  uint4 A[16];
  {
    const uint4* Ag = (const uint4*)(Kuqw + (size_t)(16 * w + arow) * 512);
    #pragma unroll
    for (int kt = 0; kt < 16; ++kt) A[kt] = Ag[kt * 4 + lg];
  }
  const int bcol = tid & 15, sub = tid >> 4;
  for (int tile = 0; tile < 8; ++tile) {
    const int pb = p0 + tile * 16;
    {
      const int pos = tid >> 5, np = tid & 31;
      float2 uv = *(const float2*)&u[(size_t)(pb + pos) * 64 + np * 2];
      us[pos][np * 2]     = g * uv.x;
      us[pos][np * 2 + 1] = g * uv.y;
      if (tid < 128) ps[tid >> 3][tid & 7] = pi[(size_t)(pb + (tid >> 3)) * 8 + (tid & 7)];
    }
    __syncthreads();
    {
      float u0 = us[bcol][2 * sub], u1 = us[bcol][2 * sub + 1];
      unsigned short tmp[16];
      #pragma unroll
      for (int m = 0; m < 8; ++m) {
        float pm = ps[bcol][m];
        tmp[m]     = f2h(u0 * pm);
        tmp[8 + m] = f2h(u1 * pm);
      }
      uint4* dst = (uint4*)&q[bcol][sub * 16];
      dst[0] = *(uint4*)&tmp[0];
      dst[1] = *(uint4*)&tmp[8];
    }
    __syncthreads();
    f32x4 acc = {0.f, 0.f, 0.f, 0.f};
    #pragma unroll
    for (int kt = 0; kt < 16; ++kt) {
      uint4 bf = *(const uint4*)&q[arow][kt * 32 + lg * 8];
      acc = mfma16(A[kt], bf, acc);
    }
    {
      uint2 zp;
      zp.x = (unsigned)f2h(acc[0]) | ((unsigned)f2h(acc[1]) << 16);
      zp.y = (unsigned)f2h(acc[2]) | ((unsigned)f2h(acc[3]) << 16);
      *(uint2*)&uc[(size_t)(pb + arow) * 128 + 16 * w + lg * 4] = zp;
    }
    __syncthreads();
  }
}

// ---------------------------------------------------------------------------
// scan (MFMA, pipelined): z_{t+1} = sum_m A_m (pi_m z_t) + uc_t, 16 batches/blk.
// uc/pi group-staged (8 steps) into LDS double buffer: global loads issued at
// group start, ds_write at group end (T14) -> zero global latency in steps.
// Single barrier per step: burn-in ping-pongs slots 16/17 so read!=write slot.
// WBURN=16 (0.554^16=7e-5 truncation).  256 blocks (64 chunks x 4 bgroups).
// ---------------------------------------------------------------------------
static constexpr int LCH = 16, WBURN = 16;

__global__ void __launch_bounds__(512, 1) scan_kernel(
    const float* __restrict__ pi, const unsigned short* __restrict__ uc,
    const unsigned short* __restrict__ Ah, unsigned short* __restrict__ zbuf) {
  const int c = blockIdx.x >> 2, bg = blockIdx.x & 3;
  const int tid = threadIdx.x;
  const int w = tid >> 6, l = tid & 63, lb = l & 15, lg = l >> 4;
  const int tstore = c * LCH;
  const int t0 = (tstore >= WBURN) ? (tstore - WBURN) : 0;
  const int tend = tstore + LCH;
  const int b0 = bg * 16;
  __shared__ __align__(16) unsigned short Zh[18 * 2176];        // 78336 B
  __shared__ __align__(16) unsigned short ucs[2][8][16][136];   // 69632 B
  __shared__ __align__(16) unsigned short pis[2][8][16][12];    // 6144 B
  uint4 A[8][4];
  {
    const uint4* Ag = (const uint4*)Ah;
    const int rbase = (w * 16 + lb) * 16 + lg;
    #pragma unroll
    for (int m = 0; m < 8; ++m)
      #pragma unroll
      for (int kt = 0; kt < 4; ++kt)
        A[m][kt] = Ag[m * 2048 + rbase + kt * 4];
  }
  {
    const uint4 z4 = make_uint4(0u, 0u, 0u, 0u);
    for (int i = tid; i < 4896; i += 512) ((uint4*)Zh)[i] = z4;
  }
  // staging thread roles
  const int srow = tid >> 2, sst = srow >> 4, sb = srow & 15, sseg = tid & 3;
  const int pst = tid >> 5, pb = (tid >> 1) & 15, ph = tid & 1;   // tid<256 only
  uint4 su0, su1, su2, su3;
  float4 spv;
  auto load_group = [&](int tg) {
    const uint4* src = (const uint4*)(uc + ((size_t)(b0 + sb) * TT + tg + sst) * 128 + sseg * 32);
    su0 = src[0]; su1 = src[1]; su2 = src[2]; su3 = src[3];
    if (tid < 256)
      spv = *(const float4*)&pi[((size_t)(b0 + pb) * TT + tg + pst) * 8 + ph * 4];
  };
  auto write_group = [&](int buf) {
    uint4* dst = (uint4*)&ucs[buf][sst][sb][sseg * 32];
    dst[0] = su0; dst[1] = su1; dst[2] = su2; dst[3] = su3;
    if (tid < 256) {
      unsigned short tmp[4];
      tmp[0] = f2h(spv.x); tmp[1] = f2h(spv.y); tmp[2] = f2h(spv.z); tmp[3] = f2h(spv.w);
      *(uint2*)&pis[buf][pst][pb][ph * 4] = *(uint2*)tmp;
    }
  };
  load_group(t0);
  write_group(0);
  __syncthreads();
  const int row0 = w * 16 + lg * 4;
  for (int g = 0; g < 4; ++g) {
    const int buf = g & 1;
    const int tg = t0 + 8 * g;
    const bool more = (tg + 8) < tend;
    if (more) load_group(tg + 8);           // issue-early (T14)
    #pragma unroll
    for (int s = 0; s < 8; ++s) {
      const int t = tg + s, t1 = t + 1;
      const int islot = (t  < tstore) ? (16 + ((t  - t0) & 1)) : (t  - tstore);
      const int oslot = (t1 < tstore) ? (16 + ((t1 - t0) & 1)) : (t1 - tstore);
      uint4 zf[4];
      const unsigned short* zb = &Zh[islot * 2176 + lb * 136 + lg * 8];
      #pragma unroll
      for (int kt = 0; kt < 4; ++kt) zf[kt] = *(const uint4*)&zb[kt * 32];
      unsigned short pr[8];
      *(uint2*)&pr[0] = *(const uint2*)&pis[buf][s][lb][0];
      *(uint2*)&pr[4] = *(const uint2*)&pis[buf][s][lb][4];
      uint2 ur = *(const uint2*)&ucs[buf][s][lb][row0];
      f32x4 acc[4];
      #pragma unroll
      for (int qq = 0; qq < 4; ++qq) acc[qq] = (f32x4){0.f, 0.f, 0.f, 0.f};
      #pragma unroll
      for (int m = 0; m < 8; ++m) {
        const h1 pim = __builtin_bit_cast(h1, pr[m]);
        #pragma unroll
        for (int kt = 0; kt < 4; ++kt) {
          f16x8 bf = __builtin_bit_cast(f16x8, zf[kt]) * pim;
          acc[m & 3] = __builtin_amdgcn_mfma_f32_16x16x32_f16(
              __builtin_bit_cast(f16x8, A[m][kt]), bf, acc[m & 3], 0, 0, 0);
        }
      }
      unsigned short uu[4];
      *(uint2*)&uu[0] = ur;
      unsigned short zh4[4];
      #pragma unroll
      for (int rr = 0; rr < 4; ++rr) {
        float s2 = acc[0][rr] + acc[1][rr] + acc[2][rr] + acc[3][rr];
        s2 += h2f(uu[rr]);
        zh4[rr] = f2h(s2);
      }
      {
        uint2 zp;
        zp.x = (unsigned)zh4[0] | ((unsigned)zh4[1] << 16);
        zp.y = (unsigned)zh4[2] | ((unsigned)zh4[3] << 16);
        *(uint2*)&Zh[oslot * 2176 + lb * 136 + row0] = zp;   // oslot != islot
      }
      __syncthreads();
    }
    if (!more) break;
    write_group(buf ^ 1);                    // write-late (T14)
    __syncthreads();
  }
  // coalesced writeout of slots 0..15 -> zbuf rows tstore..tstore+15
  {
    const int pair = tid >> 1, qq = tid & 1, s = pair >> 4, bb2 = pair & 15;
    const unsigned short* src = &Zh[s * 2176 + bb2 * 136 + qq * 64];
    unsigned short* dst = &zbuf[((size_t)(b0 + bb2) * TT + tstore + s) * 128 + qq * 64];
    #pragma unroll
    for (int k = 0; k < 8; ++k) ((uint4*)dst)[k] = ((const uint4*)src)[k];
  }
}

// ---------------------------------------------------------------------------
// y (MFMA): y[p][ay] = sum_{k=n*8+m} Cw[ay][k] * (z[p][n] pi[p][m]).
// ---------------------------------------------------------------------------
__global__ void __launch_bounds__(256) y_kernel(
    const float* __restrict__ pi, const unsigned short* __restrict__ zbuf,
    const unsigned short* __restrict__ Cw, float* __restrict__ yout) {
  __shared__ __align__(16) unsigned short q[16][1032];
  __shared__ __align__(16) unsigned short zs[16][136];
  __shared__ float ps[16][9];
  const int tid = threadIdx.x;
  const int w = tid >> 6, l = tid & 63, arow = l & 15, lg = l >> 4;
  const int p0 = blockIdx.x * 128;
  uint4 A[32];
  {
    const uint4* Ag = (const uint4*)(Cw + (size_t)(16 * w + arow) * 1024);
    #pragma unroll
    for (int kt = 0; kt < 32; ++kt) A[kt] = Ag[kt * 4 + lg];
  }
  const int bcol = tid & 15, sub = tid >> 4;
  for (int tile = 0; tile < 8; ++tile) {
    const int pb = p0 + tile * 16;
    {
      const int pos = tid >> 4, seg = tid & 15;
      *(uint4*)&zs[pos][seg * 8] = *(const uint4*)&zbuf[(size_t)(pb + pos) * 128 + seg * 8];
      if (tid < 128) ps[tid >> 3][tid & 7] = pi[(size_t)(pb + (tid >> 3)) * 8 + (tid & 7)];
    }
    __syncthreads();
    {
      unsigned short zarr[8];
      *(uint4*)zarr = *(const uint4*)&zs[bcol][sub * 8];
      float pm[8];
      #pragma unroll
      for (int m = 0; m < 8; ++m) pm[m] = ps[bcol][m];
      #pragma unroll
      for (int nn = 0; nn < 8; ++nn) {
        float zf = h2f(zarr[nn]);
        unsigned short tmp[8];
        #pragma unroll
        for (int m = 0; m < 8; ++m) tmp[m] = f2h(zf * pm[m]);
        *(uint4*)&q[bcol][sub * 64 + nn * 8] = *(uint4*)tmp;
      }
    }
    __syncthreads();
    f32x4 acc = {0.f, 0.f, 0.f, 0.f};
    #pragma unroll
    for (int kt = 0; kt < 32; ++kt) {
      uint4 bf = *(const uint4*)&q[arow][kt * 32 + lg * 8];
      acc = mfma16(A[kt], bf, acc);
    }
    *(f32x4*)&yout[(size_t)(pb + arow) * 64 + 16 * w + lg * 4] = acc;
    __syncthreads();
  }
}

// ---------------------------------------------------------------------------
// x (MFMA): x[p][i] = sum_j Sinv[i][j] z[p][j].  M=128 (8 waves), K=128.
// ---------------------------------------------------------------------------
__global__ void __launch_bounds__(512) x_kernel(
    const unsigned short* __restrict__ zbuf, const unsigned short* __restrict__ Sinvh,
    float* __restrict__ xout) {
  const int tid = threadIdx.x;
  const int w = tid >> 6, l = tid & 63, arow = l & 15, lg = l >> 4;
  const int p0 = blockIdx.x * 128;
  uint4 A[4];
  {
    const uint4* Ag = (const uint4*)(Sinvh + (size_t)(16 * w + arow) * 128);
    #pragma unroll
    for (int kt = 0; kt < 4; ++kt) A[kt] = Ag[kt * 4 + lg];
  }
  for (int tile = 0; tile < 8; ++tile) {
    const int pb = p0 + tile * 16;
    const uint4* Z = (const uint4*)(zbuf + (size_t)(pb + arow) * 128);
    f32x4 acc = {0.f, 0.f, 0.f, 0.f};
    #pragma unroll
    for (int kt = 0; kt < 4; ++kt) {
      acc = mfma16(A[kt], Z[kt * 4 + lg], acc);
    }
    *(f32x4*)&xout[(size_t)(pb + arow) * 128 + 16 * w + lg * 4] = acc;
  }
}

// ---------------------------------------------------------------------------
extern "C" void kernel_launch(void* const* d_in, const int* in_sizes, int n_in,
                              void* d_out, int out_size, void* d_ws, size_t ws_size,
                              hipStream_t stream) {
  const float* u      = (const float*)d_in[0];
  const float* K_raw  = (const float*)d_in[1];
  const float* lgam   = (const float*)d_in[2];
  const float* S_raw  = (const float*)d_in[3];
  const float* gw1    = (const float*)d_in[4];
  const float* gb1    = (const float*)d_in[5];
  const float* gw2    = (const float*)d_in[6];
  const float* gb2    = (const float*)d_in[7];

  char* w = (char*)d_ws;
  size_t off = 0;
  auto carve = [&](size_t bytes) -> void* {
    void* p = (void*)(w + off);
    off += (bytes + 255) & ~(size_t)255;
    return p;
  };
  float* pi            = (float*)carve((size_t)NPOS * 8 * 4);            // 2MB
  unsigned short* uc   = (unsigned short*)carve((size_t)NPOS * 128 * 2); // 16MB
  unsigned short* zbuf = (unsigned short*)carve((size_t)NPOS * 128 * 2); // 16MB
  unsigned short* Ah   = (unsigned short*)carve(8 * 128 * 128 * 2);
  unsigned short* Kuqw = (unsigned short*)carve(128 * 512 * 2);
  unsigned short* Cw   = (unsigned short*)carve(64 * 1024 * 2);
  unsigned short* Svh  = (unsigned short*)carve(128 * 128 * 2);

  float* yout = (float*)d_out;
  float* xout = yout + (size_t)NPOS * 64;

  prep_expert_kernel<<<dim3(8),   dim3(768), 0, stream>>>(K_raw, Ah, Kuqw, Cw);
  prep_sinv_kernel  <<<dim3(1),   dim3(256), 0, stream>>>(S_raw, Svh);
  pi_kernel  <<<dim3(1024), dim3(256),  0, stream>>>(u, gw1, gb1, gw2, gb2, pi);
  uc_kernel  <<<dim3(512),  dim3(512),  0, stream>>>(u, pi, lgam, Kuqw, uc);
  scan_kernel<<<dim3(256),  dim3(512),  0, stream>>>(pi, uc, Ah, zbuf);
  y_kernel   <<<dim3(512),  dim3(256),  0, stream>>>(pi, zbuf, Cw, yout);
  x_kernel   <<<dim3(512),  dim3(512),  0, stream>>>(zbuf, Svh, xout);
}

// Round 7
// 172.568 us; speedup vs baseline: 5.3294x; 1.1989x over previous
//
#include <hip/hip_runtime.h>
#include <math.h>

// ExpertSelectiveTimeVaryingSSM — MI355X
// prep (merged expert+sinv) -> pi (MFMA) -> uc (MFMA) -> scan (MFMA, acc-side
// pi-weighting, group-staged LDS pipeline) -> y (MFMA) -> x (MFMA).
// Math: z_{t+1} = sum_m pi_m A_m z_t + uc_t ;  y_t = sum_m pi_m C_m z_t ;
//       x_t = S^-1 z_t.  Flattened k = n*8+m folds the pi-weighted expert sum
//       into plain GEMMs for uc and y.

static constexpr int BB = 64, TT = 1024;
static constexpr int NPOS = BB * TT;           // 65536

typedef _Float16 h1;
typedef _Float16 h2v  __attribute__((ext_vector_type(2)));
typedef _Float16 f16x8 __attribute__((ext_vector_type(8)));
typedef float    f32x4 __attribute__((ext_vector_type(4)));

__device__ __forceinline__ float fdot2(unsigned int a, unsigned int b, float c) {
  return __builtin_amdgcn_fdot2(__builtin_bit_cast(h2v, a), __builtin_bit_cast(h2v, b), c, false);
}
__device__ __forceinline__ unsigned short f2h(float x) {
  h1 h = (h1)x; return __builtin_bit_cast(unsigned short, h);
}
__device__ __forceinline__ float h2f(unsigned short x) {
  return (float)__builtin_bit_cast(h1, x);
}
__device__ __forceinline__ f32x4 mfma16(uint4 a, uint4 b, f32x4 c) {
  return __builtin_amdgcn_mfma_f32_16x16x32_f16(
      __builtin_bit_cast(f16x8, a), __builtin_bit_cast(f16x8, b), c, 0, 0, 0);
}

// ---------------------------------------------------------------------------
// prep (merged): blocks 0..7 = experts (power iteration, scaled f16 repacks);
// block 8 = S^-1 by blocked forward substitution (work in tid<256, barriers
// uniform across 768).
// Outputs: Ah[m][a][n]; Kuqw[a][n*8+m]; Cw[ay][n*8+m]; Sinvh[i][j] [128][128].
// ---------------------------------------------------------------------------
__global__ void __launch_bounds__(768) prep_kernel(
    const float* __restrict__ K_raw, const float* __restrict__ S_raw,
    unsigned short* __restrict__ Ah, unsigned short* __restrict__ Kuqw,
    unsigned short* __restrict__ Cw, unsigned short* __restrict__ Sinvh) {
  __shared__ __align__(16) char pool[155424];
  const int blk = blockIdx.x, tid = threadIdx.x;
  if (blk == 8) {
    float* Sl   = (float*)pool;                      // 65536 B
    float* Ycm  = (float*)(pool + 65536);            // 128*134*4 = 68608 B
    float* invd = (float*)(pool + 65536 + 68608);    // 512 B
    float* accl = invd + 128;                        // 4096 B
    for (int idx = tid; idx < 16384; idx += 768) Sl[idx] = S_raw[idx];
    __syncthreads();
    if (tid < 128) {
      float d = Sl[tid * 128 + tid];
      float sp = (d > 20.f) ? d : log1pf(expf(d));
      invd[tid] = 1.f / (sp + 1e-3f);
    }
    __syncthreads();
    const int c = tid & 127, rh = (tid >> 7) & 1;
    const bool act = (tid < 256);
    for (int bi = 0; bi < 16; ++bi) {
      const int J = bi * 8;
      float acc4[4] = {0.f, 0.f, 0.f, 0.f};
      if (act) {
        for (int j = 0; j < J; j += 2) {
          float2 yv = *(const float2*)&Ycm[c * 134 + j];
          #pragma unroll
          for (int k = 0; k < 4; ++k) {
            float2 sv = *(const float2*)&Sl[(J + rh * 4 + k) * 128 + j];
            acc4[k] += sv.x * yv.x + sv.y * yv.y;
          }
        }
        #pragma unroll
        for (int k = 0; k < 4; ++k) accl[(rh * 4 + k) * 128 + c] = acc4[k];
      }
      __syncthreads();
      if (tid < 128) {
        float a8[8], y8[8];
        #pragma unroll
        for (int qq = 0; qq < 8; ++qq) a8[qq] = accl[qq * 128 + c];
        #pragma unroll
        for (int qq = 0; qq < 8; ++qq) {
          float s = ((c == J + qq) ? 1.f : 0.f) - a8[qq];
          #pragma unroll
          for (int p = 0; p < 8; ++p)
            if (p < qq) s -= Sl[(J + qq) * 128 + (J + p)] * y8[p];
          y8[qq] = s * invd[J + qq];
        }
        #pragma unroll
        for (int k = 0; k < 4; ++k)
          *(float2*)&Ycm[c * 134 + J + 2 * k] = make_float2(y8[2 * k], y8[2 * k + 1]);
      }
      __syncthreads();
    }
    for (int idx = tid; idx < 16384; idx += 768) {
      int i = idx >> 7, j = idx & 127;
      Sinvh[idx] = f2h(Ycm[j * 134 + i]);            // transpose back to [i][j]
    }
    return;
  }
  // ----- expert branch -----
  unsigned short* Kh  = (unsigned short*)pool;             // 76800 B
  unsigned short* KhT = (unsigned short*)(pool + 76800);   // 76800 B
  unsigned short* vh  = (unsigned short*)(pool + 153600);  // 400 B
  unsigned short* wh  = (unsigned short*)(pool + 154000);  // 400 B
  float* red          = (float*)(pool + 154400);           // 1024 B
  const float* K = K_raw + blk * 36864;
  for (int idx = tid; idx < 36864; idx += 768) {
    int r = idx / 192, n = idx - r * 192;
    float kv = K[idx];
    if (r >= 128 && n >= 128) kv = 0.f;      // zeroed u->y block
    unsigned short h = f2h(kv);
    Kh[r * 200 + n] = h;
    KhT[n * 200 + r] = h;
  }
  {
    const uint4 z4 = make_uint4(0u, 0u, 0u, 0u);
    for (int r = tid; r < 192; r += 768) {
      *(uint4*)&Kh[r * 200 + 192] = z4;
      *(uint4*)&KhT[r * 200 + 192] = z4;
    }
    if (tid < 8) { vh[192 + tid] = 0; wh[192 + tid] = 0; }
    if (tid < 192) vh[tid] = f2h(1.f);
  }
  __syncthreads();
  const int r = tid >> 2, q = tid & 3;       // 768 = 192 rows x 4 quarters
  auto matvec = [&](const unsigned short* M, const unsigned short* src,
                    unsigned short* dst) {
    float acc = 0.f;
    const uint4* Mr = (const uint4*)(M + r * 200 + 48 * q);
    const uint4* Vv = (const uint4*)(src + 48 * q);
    #pragma unroll
    for (int j = 0; j < 6; ++j) {
      uint4 mv = Mr[j], sv = Vv[j];
      acc = fdot2(mv.x, sv.x, acc);
      acc = fdot2(mv.y, sv.y, acc);
      acc = fdot2(mv.z, sv.z, acc);
      acc = fdot2(mv.w, sv.w, acc);
    }
    acc += __shfl_xor(acc, 1, 64);
    acc += __shfl_xor(acc, 2, 64);
    if (q == 0) dst[r] = f2h(2.f * acc);     // x2 keeps f16 range w/o renorm
  };
  for (int it = 0; it < 9; ++it) {
    matvec(Kh, vh, wh);  __syncthreads();
    matvec(KhT, wh, vh); __syncthreads();
  }
  matvec(Kh, vh, wh);  __syncthreads();      // final half-step: w = 2 K v
  float aw = (tid < 192) ? h2f(wh[tid]) : 0.f;
  float av = (tid < 192) ? h2f(vh[tid]) : 0.f;
  if (tid < 256) red[tid] = aw * aw;
  __syncthreads();
  for (int st = 128; st > 0; st >>= 1) { if (tid < st) red[tid] += red[tid + st]; __syncthreads(); }
  const float nw2 = red[0];
  __syncthreads();
  if (tid < 256) red[tid] = av * av;
  __syncthreads();
  for (int st = 128; st > 0; st >>= 1) { if (tid < st) red[tid] += red[tid + st]; __syncthreads(); }
  const float nv2 = red[0];
  const float sigma = sqrtf(nw2 / (4.f * nv2 + 1e-30f));   // ||Kv||/||v||
  const float inv = (sigma > 1.f) ? 1.f / sigma : 1.f;
  __syncthreads();
  for (int idx = tid; idx < 16384; idx += 768) {       // Ah: [m][a][n]
    int a = idx >> 7, n = idx & 127;
    Ah[blk * 16384 + idx] = f2h(h2f(Kh[a * 200 + n]) * inv);
  }
  for (int idx = tid; idx < 8192; idx += 768) {        // Kuqw: [a][n*8+m]
    int a = idx >> 6, n = idx & 63;
    Kuqw[a * 512 + n * 8 + blk] = f2h(h2f(Kh[a * 200 + 128 + n]) * inv);
  }
  for (int idx = tid; idx < 8192; idx += 768) {        // Cw: [ay][n*8+m]
    int ay = idx >> 7, n = idx & 127;
    Cw[ay * 1024 + n * 8 + blk] = f2h(h2f(Kh[(128 + ay) * 200 + n]) * inv);
  }
}

// ---------------------------------------------------------------------------
// pi (MFMA): h = gelu(u@gw1^T+gb1) [2 MFMA/wave/tile], logits = h@gw2^T+gb2
// [2 MFMA, gw2 zero-padded 8->16 rows], softmax via one shfl_xor(16) pair.
// 1024 blocks x 256 thr (4 waves), 64 pos/block (4 tiles of 16).
// ---------------------------------------------------------------------------
__global__ void __launch_bounds__(256) pi_kernel(
    const float* __restrict__ u, const float* __restrict__ gw1,
    const float* __restrict__ gb1, const float* __restrict__ gw2,
    const float* __restrict__ gb2, float* __restrict__ pi) {
  __shared__ __align__(16) unsigned short h_lds[4][16][72];   // 9216 B
  const int tid = threadIdx.x;
  const int w = tid >> 6, l = tid & 63, arow = l & 15, lg = l >> 4;
  const int p0 = blockIdx.x * 64;
  uint4 Agw1[2], Agw2[2];
  #pragma unroll
  for (int kt = 0; kt < 2; ++kt) {                 // gw1 rows 16w+arow
    const float* src = gw1 + (size_t)(16 * w + arow) * 64 + kt * 32 + lg * 8;
    unsigned short tmp[8];
    #pragma unroll
    for (int j = 0; j < 8; ++j) tmp[j] = f2h(src[j]);
    Agw1[kt] = *(uint4*)tmp;
  }
  #pragma unroll
  for (int kt = 0; kt < 2; ++kt) {                 // gw2 rows arow (<8), else 0
    unsigned short tmp[8];
    if (arow < 8) {
      const float* src = gw2 + (size_t)arow * 64 + kt * 32 + lg * 8;
      #pragma unroll
      for (int j = 0; j < 8; ++j) tmp[j] = f2h(src[j]);
    } else {
      #pragma unroll
      for (int j = 0; j < 8; ++j) tmp[j] = 0;
    }
    Agw2[kt] = *(uint4*)tmp;
  }
  float gb1v[4];
  #pragma unroll
  for (int rr = 0; rr < 4; ++rr) gb1v[rr] = gb1[16 * w + lg * 4 + rr];
  // phase 1: h tiles (each wave computes its 16 h-rows for all 4 tiles)
  #pragma unroll
  for (int tt = 0; tt < 4; ++tt) {
    const int pb = p0 + tt * 16;
    uint4 B[2];
    #pragma unroll
    for (int kt = 0; kt < 2; ++kt) {
      const float* src = u + (size_t)(pb + arow) * 64 + kt * 32 + lg * 8;
      unsigned short tmp[8];
      #pragma unroll
      for (int j = 0; j < 8; ++j) tmp[j] = f2h(src[j]);
      B[kt] = *(uint4*)tmp;
    }
    f32x4 acc = {0.f, 0.f, 0.f, 0.f};
    acc = mfma16(Agw1[0], B[0], acc);
    acc = mfma16(Agw1[1], B[1], acc);
    unsigned short hh[4];
    #pragma unroll
    for (int rr = 0; rr < 4; ++rr) {
      float a = acc[rr] + gb1v[rr];
      float gel = 0.5f * a * (1.0f + erff(a * 0.70710678118654752f));
      hh[rr] = f2h(gel);
    }
    *(uint2*)&h_lds[tt][arow][16 * w + lg * 4] = *(uint2*)hh;
  }
  __syncthreads();
  // phase 2: wave w -> tile w.  logits col=arow(pos), row=lg*4+r (valid lg<2)
  {
    const int pb = p0 + w * 16;
    uint4 B0 = *(const uint4*)&h_lds[w][arow][lg * 8];
    uint4 B1 = *(const uint4*)&h_lds[w][arow][32 + lg * 8];
    f32x4 acc = {0.f, 0.f, 0.f, 0.f};
    acc = mfma16(Agw2[0], B0, acc);
    acc = mfma16(Agw2[1], B1, acc);
    float lo[4];
    #pragma unroll
    for (int rr = 0; rr < 4; ++rr)
      lo[rr] = acc[rr] + ((lg < 2) ? gb2[lg * 4 + rr] : 0.f);
    float mx = fmaxf(fmaxf(lo[0], lo[1]), fmaxf(lo[2], lo[3]));
    mx = fmaxf(mx, __shfl_xor(mx, 16, 64));
    float e[4];
    float ssum = 0.f;
    #pragma unroll
    for (int rr = 0; rr < 4; ++rr) { e[rr] = expf(lo[rr] - mx); ssum += e[rr]; }
    float tot = ssum + __shfl_xor(ssum, 16, 64);
    float invt = 1.f / tot;
    if (lg < 2) {
      float4 outv = make_float4(e[0] * invt, e[1] * invt, e[2] * invt, e[3] * invt);
      *(float4*)&pi[(size_t)(pb + arow) * 8 + lg * 4] = outv;
    }
  }
}

// ---------------------------------------------------------------------------
// uc (MFMA): uc[p][a] = sum_{k=n*8+m} Kuqw[a][k] * (g u[p][n] pi[p][m]).
// M=128 (8 waves x 16 rows, A in 64 VGPR/lane), K=512, 16-pos tiles.
// ---------------------------------------------------------------------------
__global__ void __launch_bounds__(512) uc_kernel(
    const float* __restrict__ u, const float* __restrict__ pi,
    const float* __restrict__ lgam, const unsigned short* __restrict__ Kuqw,
    unsigned short* __restrict__ uc) {
  __shared__ __align__(16) unsigned short q[16][520];
  __shared__ float us[16][68];
  __shared__ float ps[16][9];
  const int tid = threadIdx.x;
  const int w = tid >> 6, l = tid & 63, arow = l & 15, lg = l >> 4;
  const int p0 = blockIdx.x * 128;
  const float g = expf(lgam[0]);
  uint4 A[16];
  {
    const uint4* Ag = (const uint4*)(Kuqw + (size_t)(16 * w + arow) * 512);
    #pragma unroll
    for (int kt = 0; kt < 16; ++kt) A[kt] = Ag[kt * 4 + lg];
  }
  const int bcol = tid & 15, sub = tid >> 4;
  for (int tile = 0; tile < 8; ++tile) {
    const int pb = p0 + tile * 16;
    {
      const int pos = tid >> 5, np = tid & 31;
      float2 uv = *(const float2*)&u[(size_t)(pb + pos) * 64 + np * 2];
      us[pos][np * 2]     = g * uv.x;
      us[pos][np * 2 + 1] = g * uv.y;
      if (tid < 128) ps[tid >> 3][tid & 7] = pi[(size_t)(pb + (tid >> 3)) * 8 + (tid & 7)];
    }
    __syncthreads();
    {
      float u0 = us[bcol][2 * sub], u1 = us[bcol][2 * sub + 1];
      unsigned short tmp[16];
      #pragma unroll
      for (int m = 0; m < 8; ++m) {
        float pm = ps[bcol][m];
        tmp[m]     = f2h(u0 * pm);
        tmp[8 + m] = f2h(u1 * pm);
      }
      uint4* dst = (uint4*)&q[bcol][sub * 16];
      dst[0] = *(uint4*)&tmp[0];
      dst[1] = *(uint4*)&tmp[8];
    }
    __syncthreads();
    f32x4 acc = {0.f, 0.f, 0.f, 0.f};
    #pragma unroll
    for (int kt = 0; kt < 16; ++kt) {
      uint4 bf = *(const uint4*)&q[arow][kt * 32 + lg * 8];
      acc = mfma16(A[kt], bf, acc);
    }
    {
      uint2 zp;
      zp.x = (unsigned)f2h(acc[0]) | ((unsigned)f2h(acc[1]) << 16);
      zp.y = (unsigned)f2h(acc[2]) | ((unsigned)f2h(acc[3]) << 16);
      *(uint2*)&uc[(size_t)(pb + arow) * 128 + 16 * w + lg * 4] = zp;
    }
    __syncthreads();
  }
}

// ---------------------------------------------------------------------------
// scan (MFMA, acc-side pi): per step, acc[m] = sum_kt mfma(A[m][kt], zf[kt])
// with SHARED unscaled z B-frag (no per-expert VALU scaling of B);
// z_next = uc + sum_m pi_m * acc[m]  (32 scalar FMAs/lane).
// uc/pi group-staged (8 steps) into LDS double buffer.  Single barrier/step
// (read slot != write slot always).  WBURN=16.  256 blocks.
// ---------------------------------------------------------------------------
static constexpr int LCH = 16, WBURN = 16;

__global__ void __launch_bounds__(512, 1) scan_kernel(
    const float* __restrict__ pi, const unsigned short* __restrict__ uc,
    const unsigned short* __restrict__ Ah, unsigned short* __restrict__ zbuf) {
  const int c = blockIdx.x >> 2, bg = blockIdx.x & 3;
  const int tid = threadIdx.x;
  const int w = tid >> 6, l = tid & 63, lb = l & 15, lg = l >> 4;
  const int tstore = c * LCH;
  const int t0 = (tstore >= WBURN) ? (tstore - WBURN) : 0;
  const int tend = tstore + LCH;
  const int b0 = bg * 16;
  __shared__ __align__(16) unsigned short Zh[18 * 2176];        // 78336 B
  __shared__ __align__(16) unsigned short ucs[2][8][16][136];   // 69632 B
  __shared__ __align__(16) unsigned short pis[2][8][16][12];    // 6144 B
  uint4 A[8][4];
  {
    const uint4* Ag = (const uint4*)Ah;
    const int rbase = (w * 16 + lb) * 16 + lg;
    #pragma unroll
    for (int m = 0; m < 8; ++m)
      #pragma unroll
      for (int kt = 0; kt < 4; ++kt)
        A[m][kt] = Ag[m * 2048 + rbase + kt * 4];
  }
  {
    const uint4 z4 = make_uint4(0u, 0u, 0u, 0u);
    for (int i = tid; i < 4896; i += 512) ((uint4*)Zh)[i] = z4;
  }
  // staging thread roles
  const int srow = tid >> 2, sst = srow >> 4, sb = srow & 15, sseg = tid & 3;
  const int pst = tid >> 5, pb = (tid >> 1) & 15, ph = tid & 1;   // tid<256 only
  uint4 su0, su1, su2, su3;
  float4 spv;
  auto load_group = [&](int tg) {
    const uint4* src = (const uint4*)(uc + ((size_t)(b0 + sb) * TT + tg + sst) * 128 + sseg * 32);
    su0 = src[0]; su1 = src[1]; su2 = src[2]; su3 = src[3];
    if (tid < 256)
      spv = *(const float4*)&pi[((size_t)(b0 + pb) * TT + tg + pst) * 8 + ph * 4];
  };
  auto write_group = [&](int buf) {
    uint4* dst = (uint4*)&ucs[buf][sst][sb][sseg * 32];
    dst[0] = su0; dst[1] = su1; dst[2] = su2; dst[3] = su3;
    if (tid < 256) {
      unsigned short tmp[4];
      tmp[0] = f2h(spv.x); tmp[1] = f2h(spv.y); tmp[2] = f2h(spv.z); tmp[3] = f2h(spv.w);
      *(uint2*)&pis[buf][pst][pb][ph * 4] = *(uint2*)tmp;
    }
  };
  load_group(t0);
  write_group(0);
  __syncthreads();
  const int row0 = w * 16 + lg * 4;
  for (int g = 0; g < 4; ++g) {
    const int buf = g & 1;
    const int tg = t0 + 8 * g;
    const bool more = (tg + 8) < tend;
    if (more) load_group(tg + 8);           // issue-early (T14)
    #pragma unroll
    for (int s = 0; s < 8; ++s) {
      const int t = tg + s, t1 = t + 1;
      const int islot = (t  < tstore) ? (16 + ((t  - t0) & 1)) : (t  - tstore);
      const int oslot = (t1 < tstore) ? (16 + ((t1 - t0) & 1)) : (t1 - tstore);
      uint4 zf[4];
      const unsigned short* zb = &Zh[islot * 2176 + lb * 136 + lg * 8];
      #pragma unroll
      for (int kt = 0; kt < 4; ++kt) zf[kt] = *(const uint4*)&zb[kt * 32];
      unsigned short pr[8];
      *(uint2*)&pr[0] = *(const uint2*)&pis[buf][s][lb][0];
      *(uint2*)&pr[4] = *(const uint2*)&pis[buf][s][lb][4];
      uint2 ur = *(const uint2*)&ucs[buf][s][lb][row0];
      // 8 independent expert matvecs with SHARED unscaled B (no VALU scaling)
      f32x4 acc[8];
      #pragma unroll
      for (int m = 0; m < 8; ++m) acc[m] = (f32x4){0.f, 0.f, 0.f, 0.f};
      #pragma unroll
      for (int m = 0; m < 8; ++m) {
        #pragma unroll
        for (int kt = 0; kt < 4; ++kt)
          acc[m] = mfma16(A[m][kt], zf[kt], acc[m]);
      }
      float pw[8];
      #pragma unroll
      for (int m = 0; m < 8; ++m) pw[m] = h2f(pr[m]);
      unsigned short uu[4];
      *(uint2*)&uu[0] = ur;
      unsigned short zh4[4];
      #pragma unroll
      for (int rr = 0; rr < 4; ++rr) {
        float s2 = h2f(uu[rr]);
        #pragma unroll
        for (int m = 0; m < 8; ++m) s2 = fmaf(pw[m], acc[m][rr], s2);
        zh4[rr] = f2h(s2);
      }
      if (t1 < tend) {
        uint2 zp;
        zp.x = (unsigned)zh4[0] | ((unsigned)zh4[1] << 16);
        zp.y = (unsigned)zh4[2] | ((unsigned)zh4[3] << 16);
        *(uint2*)&Zh[oslot * 2176 + lb * 136 + row0] = zp;   // oslot != islot
      }
      __syncthreads();
    }
    if (!more) break;
    write_group(buf ^ 1);                    // write-late (T14)
    __syncthreads();
  }
  // coalesced writeout of slots 0..15 -> zbuf rows tstore..tstore+15
  {
    const int pair = tid >> 1, qq = tid & 1, s = pair >> 4, bb2 = pair & 15;
    const unsigned short* src = &Zh[s * 2176 + bb2 * 136 + qq * 64];
    unsigned short* dst = &zbuf[((size_t)(b0 + bb2) * TT + tstore + s) * 128 + qq * 64];
    #pragma unroll
    for (int k = 0; k < 8; ++k) ((uint4*)dst)[k] = ((const uint4*)src)[k];
  }
}

// ---------------------------------------------------------------------------
// y (MFMA): y[p][ay] = sum_{k=n*8+m} Cw[ay][k] * (z[p][n] pi[p][m]).
// ---------------------------------------------------------------------------
__global__ void __launch_bounds__(256) y_kernel(
    const float* __restrict__ pi, const unsigned short* __restrict__ zbuf,
    const unsigned short* __restrict__ Cw, float* __restrict__ yout) {
  __shared__ __align__(16) unsigned short q[16][1032];
  __shared__ __align__(16) unsigned short zs[16][136];
  __shared__ float ps[16][9];
  const int tid = threadIdx.x;
  const int w = tid >> 6, l = tid & 63, arow = l & 15, lg = l >> 4;
  const int p0 = blockIdx.x * 128;
  uint4 A[32];
  {
    const uint4* Ag = (const uint4*)(Cw + (size_t)(16 * w + arow) * 1024);
    #pragma unroll
    for (int kt = 0; kt < 32; ++kt) A[kt] = Ag[kt * 4 + lg];
  }
  const int bcol = tid & 15, sub = tid >> 4;
  for (int tile = 0; tile < 8; ++tile) {
    const int pb = p0 + tile * 16;
    {
      const int pos = tid >> 4, seg = tid & 15;
      *(uint4*)&zs[pos][seg * 8] = *(const uint4*)&zbuf[(size_t)(pb + pos) * 128 + seg * 8];
      if (tid < 128) ps[tid >> 3][tid & 7] = pi[(size_t)(pb + (tid >> 3)) * 8 + (tid & 7)];
    }
    __syncthreads();
    {
      unsigned short zarr[8];
      *(uint4*)zarr = *(const uint4*)&zs[bcol][sub * 8];
      float pm[8];
      #pragma unroll
      for (int m = 0; m < 8; ++m) pm[m] = ps[bcol][m];
      #pragma unroll
      for (int nn = 0; nn < 8; ++nn) {
        float zf = h2f(zarr[nn]);
        unsigned short tmp[8];
        #pragma unroll
        for (int m = 0; m < 8; ++m) tmp[m] = f2h(zf * pm[m]);
        *(uint4*)&q[bcol][sub * 64 + nn * 8] = *(uint4*)tmp;
      }
    }
    __syncthreads();
    f32x4 acc = {0.f, 0.f, 0.f, 0.f};
    #pragma unroll
    for (int kt = 0; kt < 32; ++kt) {
      uint4 bf = *(const uint4*)&q[arow][kt * 32 + lg * 8];
      acc = mfma16(A[kt], bf, acc);
    }
    *(f32x4*)&yout[(size_t)(pb + arow) * 64 + 16 * w + lg * 4] = acc;
    __syncthreads();
  }
}

// ---------------------------------------------------------------------------
// x (MFMA): x[p][i] = sum_j Sinv[i][j] z[p][j].  M=128 (8 waves), K=128.
// ---------------------------------------------------------------------------
__global__ void __launch_bounds__(512) x_kernel(
    const unsigned short* __restrict__ zbuf, const unsigned short* __restrict__ Sinvh,
    float* __restrict__ xout) {
  const int tid = threadIdx.x;
  const int w = tid >> 6, l = tid & 63, arow = l & 15, lg = l >> 4;
  const int p0 = blockIdx.x * 128;
  uint4 A[4];
  {
    const uint4* Ag = (const uint4*)(Sinvh + (size_t)(16 * w + arow) * 128);
    #pragma unroll
    for (int kt = 0; kt < 4; ++kt) A[kt] = Ag[kt * 4 + lg];
  }
  for (int tile = 0; tile < 8; ++tile) {
    const int pb = p0 + tile * 16;
    const uint4* Z = (const uint4*)(zbuf + (size_t)(pb + arow) * 128);
    f32x4 acc = {0.f, 0.f, 0.f, 0.f};
    #pragma unroll
    for (int kt = 0; kt < 4; ++kt) {
      acc = mfma16(A[kt], Z[kt * 4 + lg], acc);
    }
    *(f32x4*)&xout[(size_t)(pb + arow) * 128 + 16 * w + lg * 4] = acc;
  }
}

// ---------------------------------------------------------------------------
extern "C" void kernel_launch(void* const* d_in, const int* in_sizes, int n_in,
                              void* d_out, int out_size, void* d_ws, size_t ws_size,
                              hipStream_t stream) {
  const float* u      = (const float*)d_in[0];
  const float* K_raw  = (const float*)d_in[1];
  const float* lgam   = (const float*)d_in[2];
  const float* S_raw  = (const float*)d_in[3];
  const float* gw1    = (const float*)d_in[4];
  const float* gb1    = (const float*)d_in[5];
  const float* gw2    = (const float*)d_in[6];
  const float* gb2    = (const float*)d_in[7];

  char* w = (char*)d_ws;
  size_t off = 0;
  auto carve = [&](size_t bytes) -> void* {
    void* p = (void*)(w + off);
    off += (bytes + 255) & ~(size_t)255;
    return p;
  };
  float* pi            = (float*)carve((size_t)NPOS * 8 * 4);            // 2MB
  unsigned short* uc   = (unsigned short*)carve((size_t)NPOS * 128 * 2); // 16MB
  unsigned short* zbuf = (unsigned short*)carve((size_t)NPOS * 128 * 2); // 16MB
  unsigned short* Ah   = (unsigned short*)carve(8 * 128 * 128 * 2);
  unsigned short* Kuqw = (unsigned short*)carve(128 * 512 * 2);
  unsigned short* Cw   = (unsigned short*)carve(64 * 1024 * 2);
  unsigned short* Svh  = (unsigned short*)carve(128 * 128 * 2);

  float* yout = (float*)d_out;
  float* xout = yout + (size_t)NPOS * 64;

  prep_kernel<<<dim3(9),    dim3(768),  0, stream>>>(K_raw, S_raw, Ah, Kuqw, Cw, Svh);
  pi_kernel  <<<dim3(1024), dim3(256),  0, stream>>>(u, gw1, gb1, gw2, gb2, pi);
  uc_kernel  <<<dim3(512),  dim3(512),  0, stream>>>(u, pi, lgam, Kuqw, uc);
  scan_kernel<<<dim3(256),  dim3(512),  0, stream>>>(pi, uc, Ah, zbuf);
  y_kernel   <<<dim3(512),  dim3(256),  0, stream>>>(pi, zbuf, Cw, yout);
  x_kernel   <<<dim3(512),  dim3(512),  0, stream>>>(zbuf, Svh, xout);
}